// Round 7
// baseline (437.203 us; speedup 1.0000x reference)
//
#include <hip/hip_runtime.h>
#include <math.h>

typedef short short8 __attribute__((ext_vector_type(8)));
typedef float floatx4 __attribute__((ext_vector_type(4)));
typedef unsigned short ushort_t;
typedef unsigned int uint_t;

// ---- problem constants ----
constexpr int BATCH   = 2;
constexpr int DIM     = 320;
constexpr int NHEADS  = 8;
constexpr int DH      = 40;
constexpr int NGROUPS = 32;
constexpr int CPG     = 10;
constexpr int SPATIAL = 4096;
constexpr int ROWS    = BATCH * SPATIAL;   // 8192
constexpr int KVL     = 77;
constexpr int KVD     = 768;
constexpr int FF      = 1280;              // geglu half width
constexpr int TQ      = 128;               // flash q-tile

// scale(1/sqrt(40)) * log2(e): folded into Q so flash uses exp2 directly
#define QK_EXP2_SCALE 0.2281259062f

__device__ __forceinline__ ushort_t f2bf(float f) {
    uint_t u = __float_as_uint(f);
    u += 0x7FFFu + ((u >> 16) & 1u);       // RNE
    return (ushort_t)(u >> 16);
}

// async global->LDS, 16B per lane; LDS dest = wave-uniform base + lane*16
__device__ __forceinline__ void gld16(const ushort_t* g, ushort_t* l) {
    __builtin_amdgcn_global_load_lds(
        (const __attribute__((address_space(1))) void*)g,
        (__attribute__((address_space(3))) void*)l, 16, 0, 0);
}

// ---------------------------------------------------------------------------
// GroupNorm partial sums: grid (16 slices, 64 groups), atomics into stats.
// stats zeroed by wtrans_all (stream-ordered before this kernel).
// ---------------------------------------------------------------------------
__global__ __launch_bounds__(256) void gn_partial_kernel(const float* __restrict__ q,
                                                         float* __restrict__ stats) {
    int slice = blockIdx.x, bg = blockIdx.y;
    const float* base = q + (size_t)bg * (CPG * SPATIAL) + slice * 2560;
    float s = 0.f, ss = 0.f;
#pragma unroll
    for (int j = 0; j < 10; j++) {
        float v = base[j * 256 + threadIdx.x];
        s += v; ss += v * v;
    }
    __shared__ float rs[256], rss[256];
    rs[threadIdx.x] = s; rss[threadIdx.x] = ss;
    __syncthreads();
    for (int off = 128; off > 0; off >>= 1) {
        if (threadIdx.x < off) {
            rs[threadIdx.x]  += rs[threadIdx.x + off];
            rss[threadIdx.x] += rss[threadIdx.x + off];
        }
        __syncthreads();
    }
    if (threadIdx.x == 0) {
        atomicAdd(&stats[bg * 2],     rs[0]);
        atomicAdd(&stats[bg * 2 + 1], rss[0]);
    }
}

__global__ void gn_apply_transpose_kernel(const float* __restrict__ q,
                                          const float* __restrict__ stats,
                                          const float* __restrict__ gs,
                                          const float* __restrict__ gb,
                                          ushort_t* __restrict__ out) {
    __shared__ float tile[32][33];
    int l0 = blockIdx.x * 32, c0 = blockIdx.y * 32, b = blockIdx.z;
    int tx = threadIdx.x, ty = threadIdx.y;
    int c = c0 + ty;
    int g = c / CPG;
    float s  = stats[(b * NGROUPS + g) * 2];
    float ss = stats[(b * NGROUPS + g) * 2 + 1];
    const float invn = 1.f / 40960.f;
    float mean = s * invn;
    float rstd = rsqrtf(ss * invn - mean * mean + 1e-6f);
    float v = q[((size_t)(b * DIM + c)) * SPATIAL + l0 + tx];
    tile[ty][tx] = (v - mean) * rstd * gs[c] + gb[c];
    __syncthreads();
    out[((size_t)(b * SPATIAL + l0 + ty)) * DIM + c0 + tx] = f2bf(tile[tx][ty]);
}

// ---------------------------------------------------------------------------
// LayerNorm rows of 320, f32 in, bf16 out. 4 rows per 256-thread block.
// ---------------------------------------------------------------------------
__global__ __launch_bounds__(256) void ln_kernel(const float* __restrict__ x,
                                                 const float* __restrict__ sc,
                                                 const float* __restrict__ bi,
                                                 ushort_t* __restrict__ out) {
    int row = blockIdx.x * 4 + (threadIdx.x >> 6);
    int lane = threadIdx.x & 63;
    const float* xr = x + (size_t)row * DIM;
    float v[5];
    float sum = 0.f, sq = 0.f;
#pragma unroll
    for (int j = 0; j < 5; j++) {
        v[j] = xr[lane + j * 64];
        sum += v[j]; sq += v[j] * v[j];
    }
#pragma unroll
    for (int off = 32; off > 0; off >>= 1) {
        sum += __shfl_down(sum, off);
        sq  += __shfl_down(sq, off);
    }
    sum = __shfl(sum, 0); sq = __shfl(sq, 0);
    float mean = sum / (float)DIM;
    float rstd = rsqrtf(sq / (float)DIM - mean * mean + 1e-5f);
#pragma unroll
    for (int j = 0; j < 5; j++) {
        int i = lane + j * 64;
        out[(size_t)row * DIM + i] = f2bf((v[j] - mean) * rstd * sc[i] + bi[i]);
    }
}

// ---------------------------------------------------------------------------
// Weight prep fused: 12 transpose segments (f32 [K][N] -> bf16 [N][K]) +
// kv f32->bf16 convert + stats zero, all in one launch.
// ---------------------------------------------------------------------------
struct WSeg { const float* src; ushort_t* dst; int K; int N; int t0; };
struct WTab {
    WSeg s[12];
    const float* cvt_src; ushort_t* cvt_dst; int cvt_n; int cvt_t0;
    float* stats;
};

__global__ __launch_bounds__(256) void wtrans_all_kernel(WTab tab) {
    int bid = blockIdx.x;
    if (bid >= tab.cvt_t0) {
        int local = bid - tab.cvt_t0;
        int base = local * 8192;
#pragma unroll
        for (int j = 0; j < 32; j++) {
            int i = base + j * 256 + threadIdx.x;
            if (i < tab.cvt_n) tab.cvt_dst[i] = f2bf(tab.cvt_src[i]);
        }
        if (local == 0 && threadIdx.x < 128) tab.stats[threadIdx.x] = 0.f;
        return;
    }
    __shared__ float tile[32][33];
    int si = 0;
#pragma unroll
    for (int i = 1; i < 12; i++) if (bid >= tab.s[i].t0) si = i;
    WSeg sg = tab.s[si];
    int local = bid - sg.t0;
    int ntn = sg.N >> 5;
    int kt = local / ntn, nt = local - kt * ntn;
    int n0 = nt * 32, k0 = kt * 32;
    int tx = threadIdx.x & 31, ty8 = threadIdx.x >> 5;
    for (int r = ty8; r < 32; r += 8)
        tile[r][tx] = sg.src[(size_t)(k0 + r) * sg.N + n0 + tx];
    __syncthreads();
    for (int r = ty8; r < 32; r += 8)
        sg.dst[(size_t)(n0 + r) * sg.K + k0 + tx] = f2bf(tile[tx][r]);
}

// ---------------------------------------------------------------------------
// V pre-transpose: src rows [b*L + l][stride] head cols -> VT[bh][48][Lpad].
// Row 40 = ones (bf16 1.0), rows 41..47 = 0; padded keys zeroed.
// grid (Lpad/32, 16), block 256.
// ---------------------------------------------------------------------------
__global__ __launch_bounds__(256) void vtrans_kernel(const ushort_t* __restrict__ src,
                                                     ushort_t* __restrict__ dst,
                                                     int stride, int headOff,
                                                     int L, int Lpad) {
    __shared__ ushort_t tile[32][41];
    int bh = blockIdx.y, b = bh >> 3, h = bh & 7;
    int l0 = blockIdx.x * 32;
    for (int idx = threadIdx.x; idx < 32 * 40; idx += 256) {
        int l = idx / 40, d = idx - l * 40;
        ushort_t v = 0;
        if (l0 + l < L)
            v = src[(size_t)(b * L + l0 + l) * stride + headOff + h * DH + d];
        tile[l][d] = v;
    }
    __syncthreads();
    for (int idx = threadIdx.x; idx < 48 * 32; idx += 256) {
        int d = idx >> 5, li = idx & 31;
        ushort_t v;
        if (d < 40)      v = tile[li][d];
        else if (d == 40) v = 0x3F80;     // bf16 1.0 (ones column for row-sum)
        else             v = 0;
        dst[((size_t)bh * 48 + d) * Lpad + l0 + li] = v;
    }
}

// ---------------------------------------------------------------------------
// bf16 MFMA GEMM, templated M-tile (64 or 128) x 64(N) x 64(K) steps.
// global_load_lds + XOR-swizzled unpadded LDS.
// C = A[M,K] @ Wt[N,K]^T (+bias)(+resid); col scale qsc for n<ncut.
// ---------------------------------------------------------------------------
template <int TM>
__global__ __launch_bounds__(256) void gemm_bf16_kernel(
    const ushort_t* __restrict__ A, const ushort_t* __restrict__ Wt,
    const float* __restrict__ bias, const float* __restrict__ resid,
    float* __restrict__ Cf, ushort_t* __restrict__ Cb,
    int M, int N, int K, float qsc, int ncut)
{
    constexpr int G = TM / 64;          // row-groups per wave
    __shared__ __align__(16) ushort_t As[TM][64];
    __shared__ __align__(16) ushort_t Bs[64][64];
    int tid = threadIdx.x;
    int wave = tid >> 6, lane = tid & 63;
    int l15 = tid & 15, quad = lane >> 4;
    int m0 = blockIdx.x * TM, n0 = blockIdx.y * 64;
    int lrow = lane >> 3, slot = lane & 7;
    floatx4 acc[G][4] = {};

    for (int k0 = 0; k0 < K; k0 += 64) {
#pragma unroll
        for (int t = 0; t < TM / 32; t++) {
            int task = wave * (TM / 32) + t;
            int r = task * 8 + lrow;
            int gc = slot ^ (r & 7);
            gld16(&A[(size_t)(m0 + r) * K + k0 + gc * 8], &As[task * 8][0]);
        }
#pragma unroll
        for (int t = 0; t < 2; t++) {
            int task = wave * 2 + t;
            int r = task * 8 + lrow;
            int gc = slot ^ (r & 7);
            gld16(&Wt[(size_t)(n0 + r) * K + k0 + gc * 8], &Bs[task * 8][0]);
        }
        __syncthreads();
        short8 a[G][2], b[4][2];
#pragma unroll
        for (int g = 0; g < G; g++) {
            int r = (TM / 4) * wave + 16 * g + l15;
            a[g][0] = *(const short8*)&As[r][(quad ^ (r & 7)) * 8];
            a[g][1] = *(const short8*)&As[r][((4 + quad) ^ (r & 7)) * 8];
        }
#pragma unroll
        for (int t = 0; t < 4; t++) {
            int r = 16 * t + l15;
            b[t][0] = *(const short8*)&Bs[r][(quad ^ (r & 7)) * 8];
            b[t][1] = *(const short8*)&Bs[r][((4 + quad) ^ (r & 7)) * 8];
        }
#pragma unroll
        for (int g = 0; g < G; g++)
#pragma unroll
            for (int t = 0; t < 4; t++) {
                acc[g][t] = __builtin_amdgcn_mfma_f32_16x16x32_bf16(a[g][0], b[t][0], acc[g][t], 0, 0, 0);
                acc[g][t] = __builtin_amdgcn_mfma_f32_16x16x32_bf16(a[g][1], b[t][1], acc[g][t], 0, 0, 0);
            }
        __syncthreads();
    }

#pragma unroll
    for (int g = 0; g < G; g++) {
        int mrow = m0 + (TM / 4) * wave + 16 * g + quad * 4;
#pragma unroll
        for (int t = 0; t < 4; t++) {
            int n = n0 + 16 * t + l15;
            float bv = bias ? bias[n] : 0.f;
            float sc = (n < ncut) ? qsc : 1.f;
#pragma unroll
            for (int i = 0; i < 4; i++) {
                int m = mrow + i;
                float v = acc[g][t][i] + bv;
                if (resid) v += resid[(size_t)m * N + n];
                v *= sc;
                if (Cf) Cf[(size_t)m * N + n] = v;
                if (Cb) Cb[(size_t)m * N + n] = f2bf(v);
            }
        }
    }
}

// ---------------------------------------------------------------------------
// fc0+GEGLU on the 128-tile structure: dual B (value n0.., gate FF+n0..)
// ---------------------------------------------------------------------------
__global__ __launch_bounds__(256) void geglu128_kernel(
    const ushort_t* __restrict__ A, const ushort_t* __restrict__ Wt,
    const float* __restrict__ bias, ushort_t* __restrict__ C, int M)
{
    constexpr int K = 320;
    __shared__ __align__(16) ushort_t As[128][64];
    __shared__ __align__(16) ushort_t Bv[64][64];
    __shared__ __align__(16) ushort_t Bg[64][64];
    int tid = threadIdx.x;
    int wave = tid >> 6, lane = tid & 63;
    int l15 = tid & 15, quad = lane >> 4;
    int m0 = blockIdx.x * 128, n0 = blockIdx.y * 64;
    int lrow = lane >> 3, slot = lane & 7;
    floatx4 av[2][4] = {}, ag[2][4] = {};

    for (int k0 = 0; k0 < K; k0 += 64) {
#pragma unroll
        for (int t = 0; t < 4; t++) {
            int task = wave * 4 + t;
            int r = task * 8 + lrow;
            int gc = slot ^ (r & 7);
            gld16(&A[(size_t)(m0 + r) * K + k0 + gc * 8], &As[task * 8][0]);
        }
#pragma unroll
        for (int t = 0; t < 2; t++) {
            int task = wave * 2 + t;
            int r = task * 8 + lrow;
            int gc = slot ^ (r & 7);
            gld16(&Wt[(size_t)(n0 + r) * K + k0 + gc * 8],      &Bv[task * 8][0]);
            gld16(&Wt[(size_t)(FF + n0 + r) * K + k0 + gc * 8], &Bg[task * 8][0]);
        }
        __syncthreads();
        short8 a[2][2], bv[4][2], bg[4][2];
#pragma unroll
        for (int g = 0; g < 2; g++) {
            int r = 32 * wave + 16 * g + l15;
            a[g][0] = *(const short8*)&As[r][(quad ^ (r & 7)) * 8];
            a[g][1] = *(const short8*)&As[r][((4 + quad) ^ (r & 7)) * 8];
        }
#pragma unroll
        for (int t = 0; t < 4; t++) {
            int r = 16 * t + l15;
            bv[t][0] = *(const short8*)&Bv[r][(quad ^ (r & 7)) * 8];
            bv[t][1] = *(const short8*)&Bv[r][((4 + quad) ^ (r & 7)) * 8];
            bg[t][0] = *(const short8*)&Bg[r][(quad ^ (r & 7)) * 8];
            bg[t][1] = *(const short8*)&Bg[r][((4 + quad) ^ (r & 7)) * 8];
        }
#pragma unroll
        for (int g = 0; g < 2; g++)
#pragma unroll
            for (int t = 0; t < 4; t++) {
                av[g][t] = __builtin_amdgcn_mfma_f32_16x16x32_bf16(a[g][0], bv[t][0], av[g][t], 0, 0, 0);
                av[g][t] = __builtin_amdgcn_mfma_f32_16x16x32_bf16(a[g][1], bv[t][1], av[g][t], 0, 0, 0);
                ag[g][t] = __builtin_amdgcn_mfma_f32_16x16x32_bf16(a[g][0], bg[t][0], ag[g][t], 0, 0, 0);
                ag[g][t] = __builtin_amdgcn_mfma_f32_16x16x32_bf16(a[g][1], bg[t][1], ag[g][t], 0, 0, 0);
            }
        __syncthreads();
    }

#pragma unroll
    for (int g = 0; g < 2; g++) {
        int mrow = m0 + 32 * wave + 16 * g + quad * 4;
#pragma unroll
        for (int t = 0; t < 4; t++) {
            int n = n0 + 16 * t + l15;
            float bb = bias[n], bgte = bias[FF + n];
#pragma unroll
            for (int i = 0; i < 4; i++) {
                float val  = av[g][t][i] + bb;
                float gate = ag[g][t][i] + bgte;
                float gl = 0.5f * gate * (1.f + erff(gate * 0.70710678118654752f));
                C[(size_t)(mrow + i) * FF + n] = f2bf(val * gl);
            }
        }
    }
}

// ---------------------------------------------------------------------------
// conv_out fused with NCHW transpose + res1: out[b][c][l] = (X2@Wt + b)[l][c] + q
// TM=64 GEMM + LDS-transposing epilogue. grid (ROWS/64, 320/64).
// ---------------------------------------------------------------------------
__global__ __launch_bounds__(256) void gemm_convout_kernel(
    const ushort_t* __restrict__ A, const ushort_t* __restrict__ Wt,
    const float* __restrict__ bias, const float* __restrict__ qres,
    float* __restrict__ out)
{
    constexpr int K = 320, N = 320;
    __shared__ __align__(16) ushort_t As[64][64];
    __shared__ __align__(16) ushort_t Bs[64][64];
    __shared__ float Cf[64][68];
    int tid = threadIdx.x;
    int wave = tid >> 6, lane = tid & 63;
    int l15 = tid & 15, quad = lane >> 4;
    int m0 = blockIdx.x * 64, n0 = blockIdx.y * 64;
    int lrow = lane >> 3, slot = lane & 7;
    floatx4 acc[4] = {};

    for (int k0 = 0; k0 < K; k0 += 64) {
#pragma unroll
        for (int t = 0; t < 2; t++) {
            int task = wave * 2 + t;
            int r = task * 8 + lrow;
            int gc = slot ^ (r & 7);
            gld16(&A[(size_t)(m0 + r) * K + k0 + gc * 8], &As[task * 8][0]);
            gld16(&Wt[(size_t)(n0 + r) * K + k0 + gc * 8], &Bs[task * 8][0]);
        }
        __syncthreads();
        short8 a0, a1, b[4][2];
        {
            int r = 16 * wave + l15;
            a0 = *(const short8*)&As[r][(quad ^ (r & 7)) * 8];
            a1 = *(const short8*)&As[r][((4 + quad) ^ (r & 7)) * 8];
        }
#pragma unroll
        for (int t = 0; t < 4; t++) {
            int r = 16 * t + l15;
            b[t][0] = *(const short8*)&Bs[r][(quad ^ (r & 7)) * 8];
            b[t][1] = *(const short8*)&Bs[r][((4 + quad) ^ (r & 7)) * 8];
        }
#pragma unroll
        for (int t = 0; t < 4; t++) {
            acc[t] = __builtin_amdgcn_mfma_f32_16x16x32_bf16(a0, b[t][0], acc[t], 0, 0, 0);
            acc[t] = __builtin_amdgcn_mfma_f32_16x16x32_bf16(a1, b[t][1], acc[t], 0, 0, 0);
        }
        __syncthreads();
    }

    // epilogue: C[m][n] -> LDS [n][m] (+bias), then coalesced NCHW store + q
#pragma unroll
    for (int t = 0; t < 4; t++) {
        int n = 16 * t + l15;
        float bv = bias[n0 + n];
        int mbase = 16 * wave + 4 * quad;
#pragma unroll
        for (int i = 0; i < 4; i++)
            Cf[n][mbase + i] = acc[t][i] + bv;
    }
    __syncthreads();
    {
        int n = tid >> 2, j = tid & 3;
        int bq = m0 >> 12;            // m0 / 4096
        int l0 = m0 & 4095;
        size_t goff = ((size_t)(bq * DIM + n0 + n)) * SPATIAL + l0 + j * 16;
        const float4* qr = (const float4*)(qres + goff);
        float4* op = (float4*)(out + goff);
#pragma unroll
        for (int c = 0; c < 4; c++) {
            float4 v = *(const float4*)&Cf[n][j * 16 + c * 4];
            float4 qv = qr[c];
            v.x += qv.x; v.y += qv.y; v.z += qv.z; v.w += qv.w;
            op[c] = v;
        }
    }
}

// ---------------------------------------------------------------------------
// Small-M bf16 GEMM (cross K/V projection, M=154).
// ---------------------------------------------------------------------------
__global__ __launch_bounds__(256) void gemm_small_kernel(
    const ushort_t* __restrict__ A, const ushort_t* __restrict__ Wt,
    ushort_t* __restrict__ Cb, int M, int N, int K)
{
    __shared__ __align__(16) ushort_t As[64][72];
    __shared__ __align__(16) ushort_t Bs[64][72];
    int tid = threadIdx.x;
    int wave = tid >> 6, l15 = tid & 15, quad = (tid & 63) >> 4;
    int m0 = blockIdx.x * 64, n0 = blockIdx.y * 64;
    floatx4 acc[4] = {};

    for (int k0 = 0; k0 < K; k0 += 64) {
#pragma unroll
        for (int p = 0; p < 2; p++) {
            int lin = p * 256 + tid;
            int r = lin >> 3, c8 = (lin & 7) * 8;
            int m = m0 + r;
            short8 avv = {};
            if (m < M) avv = *(const short8*)&A[(size_t)m * K + k0 + c8];
            *(short8*)&As[r][c8] = avv;
            *(short8*)&Bs[r][c8] = *(const short8*)&Wt[(size_t)(n0 + r) * K + k0 + c8];
        }
        __syncthreads();
        short8 a0 = *(const short8*)&As[16 * wave + l15][quad * 8];
        short8 a1 = *(const short8*)&As[16 * wave + l15][32 + quad * 8];
#pragma unroll
        for (int t = 0; t < 4; t++) {
            short8 b0 = *(const short8*)&Bs[16 * t + l15][quad * 8];
            short8 b1 = *(const short8*)&Bs[16 * t + l15][32 + quad * 8];
            acc[t] = __builtin_amdgcn_mfma_f32_16x16x32_bf16(a0, b0, acc[t], 0, 0, 0);
            acc[t] = __builtin_amdgcn_mfma_f32_16x16x32_bf16(a1, b1, acc[t], 0, 0, 0);
        }
        __syncthreads();
    }
    int mrow = m0 + 16 * wave + quad * 4;
#pragma unroll
    for (int t = 0; t < 4; t++) {
        int n = n0 + 16 * t + l15;
#pragma unroll
        for (int i = 0; i < 4; i++) {
            int m = mrow + i;
            if (m < M) Cb[(size_t)m * N + n] = f2bf(acc[t][i]);
        }
    }
}

// ---------------------------------------------------------------------------
// Flash attention v4.1: reduction-free softmax, pre-transposed V
// (VT[bh][48][Lpad], ones-row at 40), all staging via global_load_lds,
// XOR-swizzled V + P LDS. grid (L/128, H, B*NPARTS); wave owns 32 q-rows.
// FIX vs v4: QPs pad chunks 5..7 are zeroed (aq[g][1] reads them; stale LDS
// from prior dispatches (convout's f32 Cf) can alias bf16 Inf/NaN -> 0*NaN=NaN
// in MFMA on graph replay).
// ---------------------------------------------------------------------------
template <int NPARTS>
__global__ __launch_bounds__(256) void flash_kernel(
    const ushort_t* __restrict__ Qg, const ushort_t* __restrict__ Kg,
    const ushort_t* __restrict__ VT, ushort_t* __restrict__ Og,
    float* __restrict__ Opart, float* __restrict__ Lpart,
    int sQ, int sKV, int Lpad, int nk)
{
    __shared__ __align__(16) ushort_t QPs[8][130][8];   // Q rows 0..127, then P (swizzled)
    __shared__ __align__(16) ushort_t Ks[8][64][8];
    __shared__ __align__(16) ushort_t VsT[48][64];      // [dh][key], key-chunks XOR-swizzled

    int tid = threadIdx.x;
    int wave = tid >> 6, lane = tid & 63;
    int l15 = tid & 15, quad = lane >> 4;
    int qt = blockIdx.x, h = blockIdx.y;
    int b, kp;
    if (NPARTS == 2) { b = blockIdx.z >> 1; kp = blockIdx.z & 1; }
    else             { b = blockIdx.z;      kp = 0; }
    int q0 = qt * TQ;

    const ushort_t* Qb  = Qg + (size_t)(b * SPATIAL + q0) * sQ + h * DH;
    const ushort_t* Kb  = Kg + (size_t)b * nk * sKV + h * DH;
    const ushort_t* VTb = VT + (size_t)(b * NHEADS + h) * 48 * Lpad;

    // zero pad chunks ONCE: Ks 5..7 AND QPs 5..7 (the NaN fix — see header)
    const short8 z8 = {};
    for (int i = tid; i < 3 * 64; i += 256)
        *(short8*)&Ks[5 + (i >> 6)][i & 63][0] = z8;
    for (int i = tid; i < 3 * 130; i += 256)
        *(short8*)&QPs[5 + i / 130][i % 130][0] = z8;

    // stage Q: 10 wave-tasks of 64 rows x 16B
    for (int t5 = wave; t5 < 10; t5 += 4) {
        int cid = t5 >> 1, half = t5 & 1;
        gld16(&Qb[(size_t)(half * 64 + lane) * sQ + cid * 8], &QPs[cid][half * 64][0]);
    }
    __syncthreads();

    short8 aq[2][2];
#pragma unroll
    for (int g = 0; g < 2; g++) {
        int r = 32 * wave + 16 * g + l15;
        aq[g][0] = *(const short8*)&QPs[quad][r][0];
        aq[g][1] = *(const short8*)&QPs[4 + quad][r][0];
    }

    floatx4 o[2][3] = {};

    int ntiles_all = (nk + 63) >> 6;
    int t_lo = (NPARTS == 2) ? kp * (ntiles_all >> 1) : 0;
    int t_hi = (NPARTS == 2) ? t_lo + (ntiles_all >> 1) : ntiles_all;

    for (int t = t_lo; t < t_hi; t++) {
        int k0 = t * 64;
        __syncthreads();   // protect Ks/VsT/QPs from previous iteration readers
        // K: 5 direct-to-LDS wave-tasks
        for (int c = wave; c < 5; c += 4)
            gld16(&Kb[(size_t)(k0 + lane) * sKV + c * 8], &Ks[c][0][0]);
        // V^T: 6 wave-tasks; per-lane global chunk XOR-swizzled so LDS slot s
        // of row R holds global key-chunk s^(R&7)  -> conflict-free frag reads
        for (int c = wave; c < 6; c += 4) {
            int r8 = lane >> 3;
            int gc = (lane & 7) ^ r8;
            gld16(&VTb[(size_t)(c * 8 + r8) * Lpad + k0 + gc * 8], &VsT[c * 8][0]);
        }
        __syncthreads();

        // S' = (Q*scale*log2e) K^T
        floatx4 s[2][4] = {};
#pragma unroll
        for (int tt = 0; tt < 4; tt++) {
            short8 b0 = *(const short8*)&Ks[quad][16 * tt + l15][0];
            short8 b1 = *(const short8*)&Ks[4 + quad][16 * tt + l15][0];
#pragma unroll
            for (int g = 0; g < 2; g++) {
                s[g][tt] = __builtin_amdgcn_mfma_f32_16x16x32_bf16(aq[g][0], b0, s[g][tt], 0, 0, 0);
                s[g][tt] = __builtin_amdgcn_mfma_f32_16x16x32_bf16(aq[g][1], b1, s[g][tt], 0, 0, 0);
            }
        }

        // p = exp2(s'); store P (trunc-bf16) into swizzled A-layout; no reductions
        bool full = (k0 + 64 <= nk);
#pragma unroll
        for (int g = 0; g < 2; g++) {
#pragma unroll
            for (int i = 0; i < 4; i++) {
                int row = 32 * wave + 16 * g + 4 * quad + i;
                int rw = (4 * quad + i) & 7;
#pragma unroll
                for (int tt = 0; tt < 4; tt++) {
                    float x = s[g][tt][i];
                    if (!full && (k0 + 16 * tt + l15 >= nk)) x = -1e30f;
                    float pf = exp2f(x);
                    int c = (2 * tt + (l15 >> 3)) ^ rw;
                    QPs[c][row][l15 & 7] = (ushort_t)(__float_as_uint(pf) >> 16);
                }
            }
        }

        // O += P @ [V | 1]; col 40 accumulates l.
        short8 vb[3][2];
#pragma unroll
        for (int t2 = 0; t2 < 3; t2++) {
            int R = 16 * t2 + l15;
            vb[t2][0] = *(const short8*)&VsT[R][(quad ^ (l15 & 7)) * 8];
            vb[t2][1] = *(const short8*)&VsT[R][((4 + quad) ^ (l15 & 7)) * 8];
        }
#pragma unroll
        for (int g = 0; g < 2; g++) {
            int r = 32 * wave + 16 * g + l15;
            int rw = l15 & 7;
            short8 p0 = *(const short8*)&QPs[quad ^ rw][r][0];
            short8 p1 = *(const short8*)&QPs[(4 + quad) ^ rw][r][0];
#pragma unroll
            for (int t2 = 0; t2 < 3; t2++) {
                o[g][t2] = __builtin_amdgcn_mfma_f32_16x16x32_bf16(p0, vb[t2][0], o[g][t2], 0, 0, 0);
                o[g][t2] = __builtin_amdgcn_mfma_f32_16x16x32_bf16(p1, vb[t2][1], o[g][t2], 0, 0, 0);
            }
        }
    }

    if (NPARTS == 1) {
        float inv[2][4];
#pragma unroll
        for (int g = 0; g < 2; g++)
#pragma unroll
            for (int i = 0; i < 4; i++)
                inv[g][i] = 1.f / __shfl(o[g][2][i], (lane & 48) | 8, 64);
#pragma unroll
        for (int g = 0; g < 2; g++)
#pragma unroll
            for (int t2 = 0; t2 < 3; t2++) {
                int c = 16 * t2 + l15;
                if (c < DH) {
#pragma unroll
                    for (int i = 0; i < 4; i++) {
                        size_t row = (size_t)(b * SPATIAL + q0 + 32 * wave + 16 * g + 4 * quad + i);
                        Og[row * DIM + h * DH + c] = f2bf(o[g][t2][i] * inv[g][i]);
                    }
                }
            }
    } else {
#pragma unroll
        for (int g = 0; g < 2; g++) {
#pragma unroll
            for (int t2 = 0; t2 < 3; t2++) {
                int c = 16 * t2 + l15;
                if (c < DH) {
#pragma unroll
                    for (int i = 0; i < 4; i++) {
                        size_t row = (size_t)(b * SPATIAL + q0 + 32 * wave + 16 * g + 4 * quad + i);
                        Opart[((size_t)kp * ROWS + row) * DIM + h * DH + c] = o[g][t2][i];
                    }
                }
            }
            if (l15 == 8) {
#pragma unroll
                for (int i = 0; i < 4; i++) {
                    size_t row = (size_t)(b * SPATIAL + q0 + 32 * wave + 16 * g + 4 * quad + i);
                    Lpart[((size_t)kp * ROWS + row) * NHEADS + h] = o[g][2][i];
                }
            }
        }
    }
}

// merge split-K partials: out = (o0+o1)/(l0+l1)
__global__ __launch_bounds__(320) void attn_merge_kernel(
    const float* __restrict__ Op, const float* __restrict__ Lp,
    ushort_t* __restrict__ Og)
{
    int row = blockIdx.x, c = threadIdx.x;
    int h = c / DH;
    float l = Lp[(size_t)row * NHEADS + h] + Lp[((size_t)ROWS + row) * NHEADS + h];
    float o = Op[(size_t)row * DIM + c] + Op[((size_t)ROWS + row) * DIM + c];
    Og[(size_t)row * DIM + c] = f2bf(o / l);
}

// ---------------------------------------------------------------------------
extern "C" void kernel_launch(void* const* d_in, const int* in_sizes, int n_in,
                              void* d_out, int out_size, void* d_ws, size_t ws_size,
                              hipStream_t stream) {
    (void)in_sizes; (void)n_in; (void)out_size; (void)ws_size;
    const float* q      = (const float*)d_in[0];
    const float* kv     = (const float*)d_in[1];
    const float* gn_s   = (const float*)d_in[2];
    const float* gn_b   = (const float*)d_in[3];
    const float* cin_w  = (const float*)d_in[4];
    const float* cin_b  = (const float*)d_in[5];
    const float* ln0_s  = (const float*)d_in[6];
    const float* ln0_b  = (const float*)d_in[7];
    const float* a1_wq  = (const float*)d_in[8];
    const float* a1_wk  = (const float*)d_in[9];
    const float* a1_wv  = (const float*)d_in[10];
    const float* a1_wo  = (const float*)d_in[11];
    const float* a1_bo  = (const float*)d_in[12];
    const float* ln1_s  = (const float*)d_in[13];
    const float* ln1_b  = (const float*)d_in[14];
    const float* a2_wq  = (const float*)d_in[15];
    const float* a2_wk  = (const float*)d_in[16];
    const float* a2_wv  = (const float*)d_in[17];
    const float* a2_wo  = (const float*)d_in[18];
    const float* a2_bo  = (const float*)d_in[19];
    const float* lnA_s  = (const float*)d_in[20];
    const float* lnA_b  = (const float*)d_in[21];
    const float* fc0_w  = (const float*)d_in[22];
    const float* fc0_b  = (const float*)d_in[23];
    const float* fc1_w  = (const float*)d_in[24];
    const float* fc1_b  = (const float*)d_in[25];
    const float* cout_w = (const float*)d_in[26];
    const float* cout_b = (const float*)d_in[27];
    float* out = (float*)d_out;

    // ---- workspace carve ----
    char* p = (char*)d_ws;
    auto carve = [&](size_t bytes) -> char* {
        char* r = p;
        p += (bytes + 255) & ~(size_t)255;
        return r;
    };
    float*    stats  = (float*)carve(512);
    float*    B0     = (float*)carve((size_t)ROWS * DIM * 4);
    ushort_t* gnO    = (ushort_t*)carve((size_t)ROWS * DIM * 2);
    ushort_t* ln0O   = (ushort_t*)carve((size_t)ROWS * DIM * 2);
    ushort_t* QKV    = (ushort_t*)carve((size_t)ROWS * 960 * 2);
    ushort_t* attnO  = (ushort_t*)carve((size_t)ROWS * DIM * 2);
    ushort_t* ln1O   = (ushort_t*)carve((size_t)ROWS * DIM * 2);
    ushort_t* Q2     = (ushort_t*)carve((size_t)ROWS * DIM * 2);
    ushort_t* KVc    = (ushort_t*)carve((size_t)BATCH * KVL * 640 * 2);
    ushort_t* lnAO   = (ushort_t*)carve((size_t)ROWS * DIM * 2);
    ushort_t* GLU    = (ushort_t*)carve((size_t)ROWS * FF * 2);
    ushort_t* X2     = (ushort_t*)carve((size_t)ROWS * DIM * 2);
    ushort_t* kvbf   = (ushort_t*)carve((size_t)BATCH * KVL * KVD * 2);
    ushort_t* VTs    = (ushort_t*)carve((size_t)16 * 48 * SPATIAL * 2);  // self V^T
    ushort_t* VTc    = (ushort_t*)carve((size_t)16 * 48 * 128 * 2);      // cross V^T
    ushort_t* qkv_t  = (ushort_t*)carve((size_t)960 * 320 * 2);
    ushort_t* cin_t  = (ushort_t*)carve((size_t)320 * 320 * 2);
    ushort_t* a1wo_t = (ushort_t*)carve((size_t)320 * 320 * 2);
    ushort_t* a2wq_t = (ushort_t*)carve((size_t)320 * 320 * 2);
    ushort_t* kvx_t  = (ushort_t*)carve((size_t)640 * 768 * 2);
    ushort_t* a2wo_t = (ushort_t*)carve((size_t)320 * 320 * 2);
    ushort_t* fc0_t  = (ushort_t*)carve((size_t)2560 * 320 * 2);
    ushort_t* fc1_t  = (ushort_t*)carve((size_t)320 * 1280 * 2);
    ushort_t* cout_t = (ushort_t*)carve((size_t)320 * 320 * 2);
    // split-K partials alias phase-disjoint buffers
    float* Opart = (float*)GLU;    // 2 * ROWS * DIM f32 = 21.0 MB == GLU size
    float* Lpart = (float*)gnO;    // 2 * ROWS * 8 f32

    auto gemm64 = [&](const ushort_t* A, const ushort_t* Wt, const float* bias,
                      const float* resid, float* Cf, ushort_t* Cb,
                      int M, int N, int K, float qsc = 1.f, int ncut = 0) {
        gemm_bf16_kernel<64><<<dim3(M / 64, N / 64), 256, 0, stream>>>(
            A, Wt, bias, resid, Cf, Cb, M, N, K, qsc, ncut);
    };
    auto gemm128 = [&](const ushort_t* A, const ushort_t* Wt, const float* bias,
                       const float* resid, float* Cf, ushort_t* Cb,
                       int M, int N, int K, float qsc = 1.f, int ncut = 0) {
        gemm_bf16_kernel<128><<<dim3(M / 128, N / 64), 256, 0, stream>>>(
            A, Wt, bias, resid, Cf, Cb, M, N, K, qsc, ncut);
    };

    // ---- fused weight prep (+ kv cvt + stats zero) ----
    {
        WTab tab;
        int t0 = 0;
        auto seg = [&](int i, const float* s, ushort_t* d, int K, int N) {
            tab.s[i] = {s, d, K, N, t0};
            t0 += (K / 32) * (N / 32);
        };
        seg(0,  cin_w,  cin_t,             320, 320);
        seg(1,  a1_wq,  qkv_t,             320, 320);
        seg(2,  a1_wk,  qkv_t + 320 * 320, 320, 320);
        seg(3,  a1_wv,  qkv_t + 640 * 320, 320, 320);
        seg(4,  a1_wo,  a1wo_t,            320, 320);
        seg(5,  a2_wq,  a2wq_t,            320, 320);
        seg(6,  a2_wk,  kvx_t,             768, 320);
        seg(7,  a2_wv,  kvx_t + 320 * 768, 768, 320);
        seg(8,  a2_wo,  a2wo_t,            320, 320);
        seg(9,  fc0_w,  fc0_t,             320, 2560);
        seg(10, fc1_w,  fc1_t,             1280, 320);
        seg(11, cout_w, cout_t,            320, 320);
        tab.cvt_src = kv; tab.cvt_dst = kvbf;
        tab.cvt_n = BATCH * KVL * KVD; tab.cvt_t0 = t0;
        tab.stats = stats;
        int ncvt_blk = (tab.cvt_n + 8191) / 8192;
        wtrans_all_kernel<<<t0 + ncvt_blk, 256, 0, stream>>>(tab);
    }

    // ---- GroupNorm + conv_in ----
    gn_partial_kernel<<<dim3(16, 64), 256, 0, stream>>>(q, stats);
    gn_apply_transpose_kernel<<<dim3(SPATIAL / 32, DIM / 32, BATCH), dim3(32, 32), 0, stream>>>(
        q, stats, gn_s, gn_b, gnO);
    gemm64(gnO, cin_t, cin_b, nullptr, B0, nullptr, ROWS, DIM, DIM);

    // ---- self-attention (split-K flash, pre-transposed V) ----
    ln_kernel<<<ROWS / 4, 256, 0, stream>>>(B0, ln0_s, ln0_b, ln0O);
    gemm128(ln0O, qkv_t, nullptr, nullptr, nullptr, QKV, ROWS, 960, DIM, QK_EXP2_SCALE, 320);
    vtrans_kernel<<<dim3(SPATIAL / 32, 16), 256, 0, stream>>>(QKV, VTs, 960, 640, SPATIAL, SPATIAL);
    flash_kernel<2><<<dim3(SPATIAL / TQ, NHEADS, BATCH * 2), 256, 0, stream>>>(
        QKV, QKV + 320, VTs, nullptr, Opart, Lpart, 960, 960, SPATIAL, SPATIAL);
    attn_merge_kernel<<<ROWS, 320, 0, stream>>>(Opart, Lpart, attnO);
    gemm64(attnO, a1wo_t, a1_bo, B0, B0, nullptr, ROWS, DIM, DIM);

    // ---- cross-attention ----
    ln_kernel<<<ROWS / 4, 256, 0, stream>>>(B0, ln1_s, ln1_b, ln1O);
    gemm64(ln1O, a2wq_t, nullptr, nullptr, nullptr, Q2, ROWS, DIM, DIM, QK_EXP2_SCALE, 320);
    gemm_small_kernel<<<dim3(3, 10), 256, 0, stream>>>(kvbf, kvx_t, KVc, BATCH * KVL, 640, KVD);
    vtrans_kernel<<<dim3(4, 16), 256, 0, stream>>>(KVc, VTc, 640, 320, KVL, 128);
    flash_kernel<1><<<dim3(SPATIAL / TQ, NHEADS, BATCH), 256, 0, stream>>>(
        Q2, KVc, VTc, attnO, nullptr, nullptr, 320, 640, 128, KVL);
    gemm64(attnO, a2wo_t, a2_bo, B0, B0, nullptr, ROWS, DIM, DIM);

    // ---- FFN (GEGLU) ----
    ln_kernel<<<ROWS / 4, 256, 0, stream>>>(B0, lnA_s, lnA_b, lnAO);
    geglu128_kernel<<<dim3(ROWS / 128, FF / 64), 256, 0, stream>>>(lnAO, fc0_t, fc0_b, GLU, ROWS);
    gemm64(GLU, fc1_t, fc1_b, B0, nullptr, X2, ROWS, DIM, FF);

    // ---- conv_out fused with NCHW transpose + res1 ----
    gemm_convout_kernel<<<dim3(ROWS / 64, DIM / 64), 256, 0, stream>>>(
        X2, cout_t, cout_b, q, out);
}

// Round 8
// 417.097 us; speedup vs baseline: 1.0482x; 1.0482x over previous
//
#include <hip/hip_runtime.h>
#include <math.h>

typedef short short8 __attribute__((ext_vector_type(8)));
typedef float floatx4 __attribute__((ext_vector_type(4)));
typedef unsigned short ushort_t;
typedef unsigned int uint_t;

// ---- problem constants ----
constexpr int BATCH   = 2;
constexpr int DIM     = 320;
constexpr int NHEADS  = 8;
constexpr int DH      = 40;
constexpr int NGROUPS = 32;
constexpr int CPG     = 10;
constexpr int SPATIAL = 4096;
constexpr int ROWS    = BATCH * SPATIAL;   // 8192
constexpr int KVL     = 77;
constexpr int KVD     = 768;
constexpr int FF      = 1280;              // geglu half width
constexpr int TQ      = 128;               // flash q-tile
constexpr int SELF_PARTS = 4;              // split-K parts for self-attn

// scale(1/sqrt(40)) * log2(e): folded into Q so flash uses exp2 directly
#define QK_EXP2_SCALE 0.2281259062f

__device__ __forceinline__ ushort_t f2bf(float f) {
    uint_t u = __float_as_uint(f);
    u += 0x7FFFu + ((u >> 16) & 1u);       // RNE
    return (ushort_t)(u >> 16);
}
__device__ __forceinline__ float bf2f(ushort_t u) {
    return __uint_as_float(((uint_t)u) << 16);
}

// async global->LDS, 16B per lane; LDS dest = wave-uniform base + lane*16
__device__ __forceinline__ void gld16(const ushort_t* g, ushort_t* l) {
    __builtin_amdgcn_global_load_lds(
        (const __attribute__((address_space(1))) void*)g,
        (__attribute__((address_space(3))) void*)l, 16, 0, 0);
}

// ---------------------------------------------------------------------------
// GroupNorm partial sums: grid (16 slices, 64 groups), atomics into stats.
// stats zeroed by wtrans_all (stream-ordered before this kernel).
// ---------------------------------------------------------------------------
__global__ __launch_bounds__(256) void gn_partial_kernel(const float* __restrict__ q,
                                                         float* __restrict__ stats) {
    int slice = blockIdx.x, bg = blockIdx.y;
    const float* base = q + (size_t)bg * (CPG * SPATIAL) + slice * 2560;
    float s = 0.f, ss = 0.f;
#pragma unroll
    for (int j = 0; j < 10; j++) {
        float v = base[j * 256 + threadIdx.x];
        s += v; ss += v * v;
    }
    __shared__ float rs[256], rss[256];
    rs[threadIdx.x] = s; rss[threadIdx.x] = ss;
    __syncthreads();
    for (int off = 128; off > 0; off >>= 1) {
        if (threadIdx.x < off) {
            rs[threadIdx.x]  += rs[threadIdx.x + off];
            rss[threadIdx.x] += rss[threadIdx.x + off];
        }
        __syncthreads();
    }
    if (threadIdx.x == 0) {
        atomicAdd(&stats[bg * 2],     rs[0]);
        atomicAdd(&stats[bg * 2 + 1], rss[0]);
    }
}

__global__ void gn_apply_transpose_kernel(const float* __restrict__ q,
                                          const float* __restrict__ stats,
                                          const float* __restrict__ gs,
                                          const float* __restrict__ gb,
                                          ushort_t* __restrict__ out) {
    __shared__ float tile[32][33];
    int l0 = blockIdx.x * 32, c0 = blockIdx.y * 32, b = blockIdx.z;
    int tx = threadIdx.x, ty = threadIdx.y;
    int c = c0 + ty;
    int g = c / CPG;
    float s  = stats[(b * NGROUPS + g) * 2];
    float ss = stats[(b * NGROUPS + g) * 2 + 1];
    const float invn = 1.f / 40960.f;
    float mean = s * invn;
    float rstd = rsqrtf(ss * invn - mean * mean + 1e-6f);
    float v = q[((size_t)(b * DIM + c)) * SPATIAL + l0 + tx];
    tile[ty][tx] = (v - mean) * rstd * gs[c] + gb[c];
    __syncthreads();
    out[((size_t)(b * SPATIAL + l0 + ty)) * DIM + c0 + tx] = f2bf(tile[tx][ty]);
}

// ---------------------------------------------------------------------------
// LayerNorm rows of 320, f32 in, bf16 out. 4 rows per 256-thread block.
// ---------------------------------------------------------------------------
__global__ __launch_bounds__(256) void ln_kernel(const float* __restrict__ x,
                                                 const float* __restrict__ sc,
                                                 const float* __restrict__ bi,
                                                 ushort_t* __restrict__ out) {
    int row = blockIdx.x * 4 + (threadIdx.x >> 6);
    int lane = threadIdx.x & 63;
    const float* xr = x + (size_t)row * DIM;
    float v[5];
    float sum = 0.f, sq = 0.f;
#pragma unroll
    for (int j = 0; j < 5; j++) {
        v[j] = xr[lane + j * 64];
        sum += v[j]; sq += v[j] * v[j];
    }
#pragma unroll
    for (int off = 32; off > 0; off >>= 1) {
        sum += __shfl_down(sum, off);
        sq  += __shfl_down(sq, off);
    }
    sum = __shfl(sum, 0); sq = __shfl(sq, 0);
    float mean = sum / (float)DIM;
    float rstd = rsqrtf(sq / (float)DIM - mean * mean + 1e-5f);
#pragma unroll
    for (int j = 0; j < 5; j++) {
        int i = lane + j * 64;
        out[(size_t)row * DIM + i] = f2bf((v[j] - mean) * rstd * sc[i] + bi[i]);
    }
}

// ---------------------------------------------------------------------------
// Weight prep fused: 12 transpose segments (f32 [K][N] -> bf16 [N][K]) +
// kv f32->bf16 convert + stats zero, all in one launch.
// ---------------------------------------------------------------------------
struct WSeg { const float* src; ushort_t* dst; int K; int N; int t0; };
struct WTab {
    WSeg s[12];
    const float* cvt_src; ushort_t* cvt_dst; int cvt_n; int cvt_t0;
    float* stats;
};

__global__ __launch_bounds__(256) void wtrans_all_kernel(WTab tab) {
    int bid = blockIdx.x;
    if (bid >= tab.cvt_t0) {
        int local = bid - tab.cvt_t0;
        int base = local * 8192;
#pragma unroll
        for (int j = 0; j < 32; j++) {
            int i = base + j * 256 + threadIdx.x;
            if (i < tab.cvt_n) tab.cvt_dst[i] = f2bf(tab.cvt_src[i]);
        }
        if (local == 0 && threadIdx.x < 128) tab.stats[threadIdx.x] = 0.f;
        return;
    }
    __shared__ float tile[32][33];
    int si = 0;
#pragma unroll
    for (int i = 1; i < 12; i++) if (bid >= tab.s[i].t0) si = i;
    WSeg sg = tab.s[si];
    int local = bid - sg.t0;
    int ntn = sg.N >> 5;
    int kt = local / ntn, nt = local - kt * ntn;
    int n0 = nt * 32, k0 = kt * 32;
    int tx = threadIdx.x & 31, ty8 = threadIdx.x >> 5;
    for (int r = ty8; r < 32; r += 8)
        tile[r][tx] = sg.src[(size_t)(k0 + r) * sg.N + n0 + tx];
    __syncthreads();
    for (int r = ty8; r < 32; r += 8)
        sg.dst[(size_t)(n0 + r) * sg.K + k0 + tx] = f2bf(tile[tx][r]);
}

// ---------------------------------------------------------------------------
// V pre-transpose: src rows [b*L + l][stride] head cols -> VT[bh][48][Lpad].
// Row 40 = ones (bf16 1.0), rows 41..47 = 0; padded keys zeroed.
// ---------------------------------------------------------------------------
__global__ __launch_bounds__(256) void vtrans_kernel(const ushort_t* __restrict__ src,
                                                     ushort_t* __restrict__ dst,
                                                     int stride, int headOff,
                                                     int L, int Lpad) {
    __shared__ ushort_t tile[32][41];
    int bh = blockIdx.y, b = bh >> 3, h = bh & 7;
    int l0 = blockIdx.x * 32;
    for (int idx = threadIdx.x; idx < 32 * 40; idx += 256) {
        int l = idx / 40, d = idx - l * 40;
        ushort_t v = 0;
        if (l0 + l < L)
            v = src[(size_t)(b * L + l0 + l) * stride + headOff + h * DH + d];
        tile[l][d] = v;
    }
    __syncthreads();
    for (int idx = threadIdx.x; idx < 48 * 32; idx += 256) {
        int d = idx >> 5, li = idx & 31;
        ushort_t v;
        if (d < 40)      v = tile[li][d];
        else if (d == 40) v = 0x3F80;     // bf16 1.0 (ones column for row-sum)
        else             v = 0;
        dst[((size_t)bh * 48 + d) * Lpad + l0 + li] = v;
    }
}

// ---------------------------------------------------------------------------
// bf16 MFMA GEMM, templated M-tile (64 or 128) x 64(N) x 64(K) steps.
// global_load_lds + XOR-swizzled unpadded LDS.
// ---------------------------------------------------------------------------
template <int TM>
__global__ __launch_bounds__(256) void gemm_bf16_kernel(
    const ushort_t* __restrict__ A, const ushort_t* __restrict__ Wt,
    const float* __restrict__ bias, const float* __restrict__ resid,
    float* __restrict__ Cf, ushort_t* __restrict__ Cb,
    int M, int N, int K, float qsc, int ncut)
{
    constexpr int G = TM / 64;          // row-groups per wave
    __shared__ __align__(16) ushort_t As[TM][64];
    __shared__ __align__(16) ushort_t Bs[64][64];
    int tid = threadIdx.x;
    int wave = tid >> 6, lane = tid & 63;
    int l15 = tid & 15, quad = lane >> 4;
    int m0 = blockIdx.x * TM, n0 = blockIdx.y * 64;
    int lrow = lane >> 3, slot = lane & 7;
    floatx4 acc[G][4] = {};

    for (int k0 = 0; k0 < K; k0 += 64) {
#pragma unroll
        for (int t = 0; t < TM / 32; t++) {
            int task = wave * (TM / 32) + t;
            int r = task * 8 + lrow;
            int gc = slot ^ (r & 7);
            gld16(&A[(size_t)(m0 + r) * K + k0 + gc * 8], &As[task * 8][0]);
        }
#pragma unroll
        for (int t = 0; t < 2; t++) {
            int task = wave * 2 + t;
            int r = task * 8 + lrow;
            int gc = slot ^ (r & 7);
            gld16(&Wt[(size_t)(n0 + r) * K + k0 + gc * 8], &Bs[task * 8][0]);
        }
        __syncthreads();
        short8 a[G][2], b[4][2];
#pragma unroll
        for (int g = 0; g < G; g++) {
            int r = (TM / 4) * wave + 16 * g + l15;
            a[g][0] = *(const short8*)&As[r][(quad ^ (r & 7)) * 8];
            a[g][1] = *(const short8*)&As[r][((4 + quad) ^ (r & 7)) * 8];
        }
#pragma unroll
        for (int t = 0; t < 4; t++) {
            int r = 16 * t + l15;
            b[t][0] = *(const short8*)&Bs[r][(quad ^ (r & 7)) * 8];
            b[t][1] = *(const short8*)&Bs[r][((4 + quad) ^ (r & 7)) * 8];
        }
#pragma unroll
        for (int g = 0; g < G; g++)
#pragma unroll
            for (int t = 0; t < 4; t++) {
                acc[g][t] = __builtin_amdgcn_mfma_f32_16x16x32_bf16(a[g][0], b[t][0], acc[g][t], 0, 0, 0);
                acc[g][t] = __builtin_amdgcn_mfma_f32_16x16x32_bf16(a[g][1], b[t][1], acc[g][t], 0, 0, 0);
            }
        __syncthreads();
    }

#pragma unroll
    for (int g = 0; g < G; g++) {
        int mrow = m0 + (TM / 4) * wave + 16 * g + quad * 4;
#pragma unroll
        for (int t = 0; t < 4; t++) {
            int n = n0 + 16 * t + l15;
            float bv = bias ? bias[n] : 0.f;
            float sc = (n < ncut) ? qsc : 1.f;
#pragma unroll
            for (int i = 0; i < 4; i++) {
                int m = mrow + i;
                float v = acc[g][t][i] + bv;
                if (resid) v += resid[(size_t)m * N + n];
                v *= sc;
                if (Cf) Cf[(size_t)m * N + n] = v;
                if (Cb) Cb[(size_t)m * N + n] = f2bf(v);
            }
        }
    }
}

// ---------------------------------------------------------------------------
// fc0+GEGLU on the 128-tile structure: dual B (value n0.., gate FF+n0..)
// ---------------------------------------------------------------------------
__global__ __launch_bounds__(256) void geglu128_kernel(
    const ushort_t* __restrict__ A, const ushort_t* __restrict__ Wt,
    const float* __restrict__ bias, ushort_t* __restrict__ C, int M)
{
    constexpr int K = 320;
    __shared__ __align__(16) ushort_t As[128][64];
    __shared__ __align__(16) ushort_t Bv[64][64];
    __shared__ __align__(16) ushort_t Bg[64][64];
    int tid = threadIdx.x;
    int wave = tid >> 6, lane = tid & 63;
    int l15 = tid & 15, quad = lane >> 4;
    int m0 = blockIdx.x * 128, n0 = blockIdx.y * 64;
    int lrow = lane >> 3, slot = lane & 7;
    floatx4 av[2][4] = {}, ag[2][4] = {};

    for (int k0 = 0; k0 < K; k0 += 64) {
#pragma unroll
        for (int t = 0; t < 4; t++) {
            int task = wave * 4 + t;
            int r = task * 8 + lrow;
            int gc = slot ^ (r & 7);
            gld16(&A[(size_t)(m0 + r) * K + k0 + gc * 8], &As[task * 8][0]);
        }
#pragma unroll
        for (int t = 0; t < 2; t++) {
            int task = wave * 2 + t;
            int r = task * 8 + lrow;
            int gc = slot ^ (r & 7);
            gld16(&Wt[(size_t)(n0 + r) * K + k0 + gc * 8],      &Bv[task * 8][0]);
            gld16(&Wt[(size_t)(FF + n0 + r) * K + k0 + gc * 8], &Bg[task * 8][0]);
        }
        __syncthreads();
        short8 a[2][2], bv[4][2], bg[4][2];
#pragma unroll
        for (int g = 0; g < 2; g++) {
            int r = 32 * wave + 16 * g + l15;
            a[g][0] = *(const short8*)&As[r][(quad ^ (r & 7)) * 8];
            a[g][1] = *(const short8*)&As[r][((4 + quad) ^ (r & 7)) * 8];
        }
#pragma unroll
        for (int t = 0; t < 4; t++) {
            int r = 16 * t + l15;
            bv[t][0] = *(const short8*)&Bv[r][(quad ^ (r & 7)) * 8];
            bv[t][1] = *(const short8*)&Bv[r][((4 + quad) ^ (r & 7)) * 8];
            bg[t][0] = *(const short8*)&Bg[r][(quad ^ (r & 7)) * 8];
            bg[t][1] = *(const short8*)&Bg[r][((4 + quad) ^ (r & 7)) * 8];
        }
#pragma unroll
        for (int g = 0; g < 2; g++)
#pragma unroll
            for (int t = 0; t < 4; t++) {
                av[g][t] = __builtin_amdgcn_mfma_f32_16x16x32_bf16(a[g][0], bv[t][0], av[g][t], 0, 0, 0);
                av[g][t] = __builtin_amdgcn_mfma_f32_16x16x32_bf16(a[g][1], bv[t][1], av[g][t], 0, 0, 0);
                ag[g][t] = __builtin_amdgcn_mfma_f32_16x16x32_bf16(a[g][0], bg[t][0], ag[g][t], 0, 0, 0);
                ag[g][t] = __builtin_amdgcn_mfma_f32_16x16x32_bf16(a[g][1], bg[t][1], ag[g][t], 0, 0, 0);
            }
        __syncthreads();
    }

#pragma unroll
    for (int g = 0; g < 2; g++) {
        int mrow = m0 + 32 * wave + 16 * g + quad * 4;
#pragma unroll
        for (int t = 0; t < 4; t++) {
            int n = n0 + 16 * t + l15;
            float bb = bias[n], bgte = bias[FF + n];
#pragma unroll
            for (int i = 0; i < 4; i++) {
                float val  = av[g][t][i] + bb;
                float gate = ag[g][t][i] + bgte;
                float gl = 0.5f * gate * (1.f + erff(gate * 0.70710678118654752f));
                C[(size_t)(mrow + i) * FF + n] = f2bf(val * gl);
            }
        }
    }
}

// ---------------------------------------------------------------------------
// conv_out fused with NCHW transpose + res1.
// ---------------------------------------------------------------------------
__global__ __launch_bounds__(256) void gemm_convout_kernel(
    const ushort_t* __restrict__ A, const ushort_t* __restrict__ Wt,
    const float* __restrict__ bias, const float* __restrict__ qres,
    float* __restrict__ out)
{
    constexpr int K = 320;
    __shared__ __align__(16) ushort_t As[64][64];
    __shared__ __align__(16) ushort_t Bs[64][64];
    __shared__ float Cf[64][68];
    int tid = threadIdx.x;
    int wave = tid >> 6, lane = tid & 63;
    int l15 = tid & 15, quad = lane >> 4;
    int m0 = blockIdx.x * 64, n0 = blockIdx.y * 64;
    int lrow = lane >> 3, slot = lane & 7;
    floatx4 acc[4] = {};

    for (int k0 = 0; k0 < K; k0 += 64) {
#pragma unroll
        for (int t = 0; t < 2; t++) {
            int task = wave * 2 + t;
            int r = task * 8 + lrow;
            int gc = slot ^ (r & 7);
            gld16(&A[(size_t)(m0 + r) * K + k0 + gc * 8], &As[task * 8][0]);
            gld16(&Wt[(size_t)(n0 + r) * K + k0 + gc * 8], &Bs[task * 8][0]);
        }
        __syncthreads();
        short8 a0, a1, b[4][2];
        {
            int r = 16 * wave + l15;
            a0 = *(const short8*)&As[r][(quad ^ (r & 7)) * 8];
            a1 = *(const short8*)&As[r][((4 + quad) ^ (r & 7)) * 8];
        }
#pragma unroll
        for (int t = 0; t < 4; t++) {
            int r = 16 * t + l15;
            b[t][0] = *(const short8*)&Bs[r][(quad ^ (r & 7)) * 8];
            b[t][1] = *(const short8*)&Bs[r][((4 + quad) ^ (r & 7)) * 8];
        }
#pragma unroll
        for (int t = 0; t < 4; t++) {
            acc[t] = __builtin_amdgcn_mfma_f32_16x16x32_bf16(a0, b[t][0], acc[t], 0, 0, 0);
            acc[t] = __builtin_amdgcn_mfma_f32_16x16x32_bf16(a1, b[t][1], acc[t], 0, 0, 0);
        }
        __syncthreads();
    }

#pragma unroll
    for (int t = 0; t < 4; t++) {
        int n = 16 * t + l15;
        float bv = bias[n0 + n];
        int mbase = 16 * wave + 4 * quad;
#pragma unroll
        for (int i = 0; i < 4; i++)
            Cf[n][mbase + i] = acc[t][i] + bv;
    }
    __syncthreads();
    {
        int n = tid >> 2, j = tid & 3;
        int bq = m0 >> 12;
        int l0 = m0 & 4095;
        size_t goff = ((size_t)(bq * DIM + n0 + n)) * SPATIAL + l0 + j * 16;
        const float4* qr = (const float4*)(qres + goff);
        float4* op = (float4*)(out + goff);
#pragma unroll
        for (int c = 0; c < 4; c++) {
            float4 v = *(const float4*)&Cf[n][j * 16 + c * 4];
            float4 qv = qr[c];
            v.x += qv.x; v.y += qv.y; v.z += qv.z; v.w += qv.w;
            op[c] = v;
        }
    }
}

// ---------------------------------------------------------------------------
// Small-M bf16 GEMM (cross K/V projection, M=154).
// ---------------------------------------------------------------------------
__global__ __launch_bounds__(256) void gemm_small_kernel(
    const ushort_t* __restrict__ A, const ushort_t* __restrict__ Wt,
    ushort_t* __restrict__ Cb, int M, int N, int K)
{
    __shared__ __align__(16) ushort_t As[64][72];
    __shared__ __align__(16) ushort_t Bs[64][72];
    int tid = threadIdx.x;
    int wave = tid >> 6, l15 = tid & 15, quad = (tid & 63) >> 4;
    int m0 = blockIdx.x * 64, n0 = blockIdx.y * 64;
    floatx4 acc[4] = {};

    for (int k0 = 0; k0 < K; k0 += 64) {
#pragma unroll
        for (int p = 0; p < 2; p++) {
            int lin = p * 256 + tid;
            int r = lin >> 3, c8 = (lin & 7) * 8;
            int m = m0 + r;
            short8 avv = {};
            if (m < M) avv = *(const short8*)&A[(size_t)m * K + k0 + c8];
            *(short8*)&As[r][c8] = avv;
            *(short8*)&Bs[r][c8] = *(const short8*)&Wt[(size_t)(n0 + r) * K + k0 + c8];
        }
        __syncthreads();
        short8 a0 = *(const short8*)&As[16 * wave + l15][quad * 8];
        short8 a1 = *(const short8*)&As[16 * wave + l15][32 + quad * 8];
#pragma unroll
        for (int t = 0; t < 4; t++) {
            short8 b0 = *(const short8*)&Bs[16 * t + l15][quad * 8];
            short8 b1 = *(const short8*)&Bs[16 * t + l15][32 + quad * 8];
            acc[t] = __builtin_amdgcn_mfma_f32_16x16x32_bf16(a0, b0, acc[t], 0, 0, 0);
            acc[t] = __builtin_amdgcn_mfma_f32_16x16x32_bf16(a1, b1, acc[t], 0, 0, 0);
        }
        __syncthreads();
    }
    int mrow = m0 + 16 * wave + quad * 4;
#pragma unroll
    for (int t = 0; t < 4; t++) {
        int n = n0 + 16 * t + l15;
#pragma unroll
        for (int i = 0; i < 4; i++) {
            int m = mrow + i;
            if (m < M) Cb[(size_t)m * N + n] = f2bf(acc[t][i]);
        }
    }
}

// ---------------------------------------------------------------------------
// Flash attention v4.2: reduction-free softmax, pre-transposed V, async
// staging, XOR-swizzled P/V LDS. NPARTS-way split-K: partials in bf16.
// grid (L/128, H, B*NPARTS); wave owns 32 q-rows.
// ---------------------------------------------------------------------------
template <int NPARTS>
__global__ __launch_bounds__(256) void flash_kernel(
    const ushort_t* __restrict__ Qg, const ushort_t* __restrict__ Kg,
    const ushort_t* __restrict__ VT, ushort_t* __restrict__ Og,
    ushort_t* __restrict__ Opart, float* __restrict__ Lpart,
    int sQ, int sKV, int Lpad, int nk)
{
    __shared__ __align__(16) ushort_t QPs[8][130][8];   // Q rows 0..127, then P (swizzled)
    __shared__ __align__(16) ushort_t Ks[8][64][8];
    __shared__ __align__(16) ushort_t VsT[48][64];      // [dh][key], key-chunks XOR-swizzled

    int tid = threadIdx.x;
    int wave = tid >> 6, lane = tid & 63;
    int l15 = tid & 15, quad = lane >> 4;
    int qt = blockIdx.x, h = blockIdx.y;
    int b, kp;
    if (NPARTS > 1) { b = blockIdx.z / NPARTS; kp = blockIdx.z % NPARTS; }
    else            { b = blockIdx.z;          kp = 0; }
    int q0 = qt * TQ;

    const ushort_t* Qb  = Qg + (size_t)(b * SPATIAL + q0) * sQ + h * DH;
    const ushort_t* Kb  = Kg + (size_t)b * nk * sKV + h * DH;
    const ushort_t* VTb = VT + (size_t)(b * NHEADS + h) * 48 * Lpad;

    // zero pad chunks ONCE: Ks 5..7 AND QPs 5..7 (NaN fix: aq[g][1] reads
    // QPs planes 4..7; stale LDS f32 data can alias bf16 NaN -> 0*NaN=NaN)
    const short8 z8 = {};
    for (int i = tid; i < 3 * 64; i += 256)
        *(short8*)&Ks[5 + (i >> 6)][i & 63][0] = z8;
    for (int i = tid; i < 3 * 130; i += 256)
        *(short8*)&QPs[5 + i / 130][i % 130][0] = z8;

    // stage Q: 10 wave-tasks of 64 rows x 16B
    for (int t5 = wave; t5 < 10; t5 += 4) {
        int cid = t5 >> 1, half = t5 & 1;
        gld16(&Qb[(size_t)(half * 64 + lane) * sQ + cid * 8], &QPs[cid][half * 64][0]);
    }
    __syncthreads();

    short8 aq[2][2];
#pragma unroll
    for (int g = 0; g < 2; g++) {
        int r = 32 * wave + 16 * g + l15;
        aq[g][0] = *(const short8*)&QPs[quad][r][0];
        aq[g][1] = *(const short8*)&QPs[4 + quad][r][0];
    }

    floatx4 o[2][3] = {};

    int ntiles_all = (nk + 63) >> 6;
    int per = ntiles_all / NPARTS;
    int t_lo = kp * per;
    int t_hi = (NPARTS > 1) ? t_lo + per : ntiles_all;

    for (int t = t_lo; t < t_hi; t++) {
        int k0 = t * 64;
        __syncthreads();
        for (int c = wave; c < 5; c += 4)
            gld16(&Kb[(size_t)(k0 + lane) * sKV + c * 8], &Ks[c][0][0]);
        for (int c = wave; c < 6; c += 4) {
            int r8 = lane >> 3;
            int gc = (lane & 7) ^ r8;
            gld16(&VTb[(size_t)(c * 8 + r8) * Lpad + k0 + gc * 8], &VsT[c * 8][0]);
        }
        __syncthreads();

        // S' = (Q*scale*log2e) K^T
        floatx4 s[2][4] = {};
#pragma unroll
        for (int tt = 0; tt < 4; tt++) {
            short8 b0 = *(const short8*)&Ks[quad][16 * tt + l15][0];
            short8 b1 = *(const short8*)&Ks[4 + quad][16 * tt + l15][0];
#pragma unroll
            for (int g = 0; g < 2; g++) {
                s[g][tt] = __builtin_amdgcn_mfma_f32_16x16x32_bf16(aq[g][0], b0, s[g][tt], 0, 0, 0);
                s[g][tt] = __builtin_amdgcn_mfma_f32_16x16x32_bf16(aq[g][1], b1, s[g][tt], 0, 0, 0);
            }
        }

        // p = exp2(s'); store P (trunc-bf16) into swizzled A-layout
        bool full = (k0 + 64 <= nk);
#pragma unroll
        for (int g = 0; g < 2; g++) {
#pragma unroll
            for (int i = 0; i < 4; i++) {
                int row = 32 * wave + 16 * g + 4 * quad + i;
                int rw = (4 * quad + i) & 7;
#pragma unroll
                for (int tt = 0; tt < 4; tt++) {
                    float x = s[g][tt][i];
                    if (!full && (k0 + 16 * tt + l15 >= nk)) x = -1e30f;
                    float pf = exp2f(x);
                    int c = (2 * tt + (l15 >> 3)) ^ rw;
                    QPs[c][row][l15 & 7] = (ushort_t)(__float_as_uint(pf) >> 16);
                }
            }
        }

        // O += P @ [V | 1]; col 40 accumulates l.
        short8 vb[3][2];
#pragma unroll
        for (int t2 = 0; t2 < 3; t2++) {
            int R = 16 * t2 + l15;
            vb[t2][0] = *(const short8*)&VsT[R][(quad ^ (l15 & 7)) * 8];
            vb[t2][1] = *(const short8*)&VsT[R][((4 + quad) ^ (l15 & 7)) * 8];
        }
#pragma unroll
        for (int g = 0; g < 2; g++) {
            int r = 32 * wave + 16 * g + l15;
            int rw = l15 & 7;
            short8 p0 = *(const short8*)&QPs[quad ^ rw][r][0];
            short8 p1 = *(const short8*)&QPs[(4 + quad) ^ rw][r][0];
#pragma unroll
            for (int t2 = 0; t2 < 3; t2++) {
                o[g][t2] = __builtin_amdgcn_mfma_f32_16x16x32_bf16(p0, vb[t2][0], o[g][t2], 0, 0, 0);
                o[g][t2] = __builtin_amdgcn_mfma_f32_16x16x32_bf16(p1, vb[t2][1], o[g][t2], 0, 0, 0);
            }
        }
    }

    if (NPARTS == 1) {
        float inv[2][4];
#pragma unroll
        for (int g = 0; g < 2; g++)
#pragma unroll
            for (int i = 0; i < 4; i++)
                inv[g][i] = 1.f / __shfl(o[g][2][i], (lane & 48) | 8, 64);
#pragma unroll
        for (int g = 0; g < 2; g++)
#pragma unroll
            for (int t2 = 0; t2 < 3; t2++) {
                int c = 16 * t2 + l15;
                if (c < DH) {
#pragma unroll
                    for (int i = 0; i < 4; i++) {
                        size_t row = (size_t)(b * SPATIAL + q0 + 32 * wave + 16 * g + 4 * quad + i);
                        Og[row * DIM + h * DH + c] = f2bf(o[g][t2][i] * inv[g][i]);
                    }
                }
            }
    } else {
        // bf16 partials (error budget: ~0.4% rel per part, absmax stays << 0.1)
#pragma unroll
        for (int g = 0; g < 2; g++) {
#pragma unroll
            for (int t2 = 0; t2 < 3; t2++) {
                int c = 16 * t2 + l15;
                if (c < DH) {
#pragma unroll
                    for (int i = 0; i < 4; i++) {
                        size_t row = (size_t)(b * SPATIAL + q0 + 32 * wave + 16 * g + 4 * quad + i);
                        Opart[((size_t)kp * ROWS + row) * DIM + h * DH + c] = f2bf(o[g][t2][i]);
                    }
                }
            }
            if (l15 == 8) {
#pragma unroll
                for (int i = 0; i < 4; i++) {
                    size_t row = (size_t)(b * SPATIAL + q0 + 32 * wave + 16 * g + 4 * quad + i);
                    Lpart[((size_t)kp * ROWS + row) * NHEADS + h] = o[g][2][i];
                }
            }
        }
    }
}

// merge split-K partials: out = (Σ o_kp) / (Σ l_kp), bf16 partials
__global__ __launch_bounds__(320) void attn_merge_kernel(
    const ushort_t* __restrict__ Op, const float* __restrict__ Lp,
    ushort_t* __restrict__ Og)
{
    int row = blockIdx.x, c = threadIdx.x;
    int h = c / DH;
    float l = 0.f, o = 0.f;
#pragma unroll
    for (int kp = 0; kp < SELF_PARTS; kp++) {
        l += Lp[((size_t)kp * ROWS + row) * NHEADS + h];
        o += bf2f(Op[((size_t)kp * ROWS + row) * DIM + c]);
    }
    Og[(size_t)row * DIM + c] = f2bf(o / l);
}

// ---------------------------------------------------------------------------
extern "C" void kernel_launch(void* const* d_in, const int* in_sizes, int n_in,
                              void* d_out, int out_size, void* d_ws, size_t ws_size,
                              hipStream_t stream) {
    (void)in_sizes; (void)n_in; (void)out_size; (void)ws_size;
    const float* q      = (const float*)d_in[0];
    const float* kv     = (const float*)d_in[1];
    const float* gn_s   = (const float*)d_in[2];
    const float* gn_b   = (const float*)d_in[3];
    const float* cin_w  = (const float*)d_in[4];
    const float* cin_b  = (const float*)d_in[5];
    const float* ln0_s  = (const float*)d_in[6];
    const float* ln0_b  = (const float*)d_in[7];
    const float* a1_wq  = (const float*)d_in[8];
    const float* a1_wk  = (const float*)d_in[9];
    const float* a1_wv  = (const float*)d_in[10];
    const float* a1_wo  = (const float*)d_in[11];
    const float* a1_bo  = (const float*)d_in[12];
    const float* ln1_s  = (const float*)d_in[13];
    const float* ln1_b  = (const float*)d_in[14];
    const float* a2_wq  = (const float*)d_in[15];
    const float* a2_wk  = (const float*)d_in[16];
    const float* a2_wv  = (const float*)d_in[17];
    const float* a2_wo  = (const float*)d_in[18];
    const float* a2_bo  = (const float*)d_in[19];
    const float* lnA_s  = (const float*)d_in[20];
    const float* lnA_b  = (const float*)d_in[21];
    const float* fc0_w  = (const float*)d_in[22];
    const float* fc0_b  = (const float*)d_in[23];
    const float* fc1_w  = (const float*)d_in[24];
    const float* fc1_b  = (const float*)d_in[25];
    const float* cout_w = (const float*)d_in[26];
    const float* cout_b = (const float*)d_in[27];
    float* out = (float*)d_out;

    // ---- workspace carve ----
    char* p = (char*)d_ws;
    auto carve = [&](size_t bytes) -> char* {
        char* r = p;
        p += (bytes + 255) & ~(size_t)255;
        return r;
    };
    float*    stats  = (float*)carve(512);
    float*    B0     = (float*)carve((size_t)ROWS * DIM * 4);
    ushort_t* gnO    = (ushort_t*)carve((size_t)ROWS * DIM * 2);
    ushort_t* ln0O   = (ushort_t*)carve((size_t)ROWS * DIM * 2);
    ushort_t* QKV    = (ushort_t*)carve((size_t)ROWS * 960 * 2);
    ushort_t* attnO  = (ushort_t*)carve((size_t)ROWS * DIM * 2);
    ushort_t* ln1O   = (ushort_t*)carve((size_t)ROWS * DIM * 2);
    ushort_t* Q2     = (ushort_t*)carve((size_t)ROWS * DIM * 2);
    ushort_t* KVc    = (ushort_t*)carve((size_t)BATCH * KVL * 640 * 2);
    ushort_t* lnAO   = (ushort_t*)carve((size_t)ROWS * DIM * 2);
    ushort_t* GLU    = (ushort_t*)carve((size_t)ROWS * FF * 2);
    ushort_t* X2     = (ushort_t*)carve((size_t)ROWS * DIM * 2);
    ushort_t* kvbf   = (ushort_t*)carve((size_t)BATCH * KVL * KVD * 2);
    ushort_t* VTs    = (ushort_t*)carve((size_t)16 * 48 * SPATIAL * 2);  // self V^T
    ushort_t* VTc    = (ushort_t*)carve((size_t)16 * 48 * 128 * 2);      // cross V^T
    ushort_t* qkv_t  = (ushort_t*)carve((size_t)960 * 320 * 2);
    ushort_t* cin_t  = (ushort_t*)carve((size_t)320 * 320 * 2);
    ushort_t* a1wo_t = (ushort_t*)carve((size_t)320 * 320 * 2);
    ushort_t* a2wq_t = (ushort_t*)carve((size_t)320 * 320 * 2);
    ushort_t* kvx_t  = (ushort_t*)carve((size_t)640 * 768 * 2);
    ushort_t* a2wo_t = (ushort_t*)carve((size_t)320 * 320 * 2);
    ushort_t* fc0_t  = (ushort_t*)carve((size_t)2560 * 320 * 2);
    ushort_t* fc1_t  = (ushort_t*)carve((size_t)320 * 1280 * 2);
    ushort_t* cout_t = (ushort_t*)carve((size_t)320 * 320 * 2);
    // split-K partials alias phase-disjoint buffers:
    // Opart bf16: 4 * ROWS * DIM * 2 B = 21.0 MB == GLU (FFN-phase only)
    ushort_t* Opart = GLU;
    float*    Lpart = (float*)gnO;   // 4 * ROWS * 8 f32 = 1.05 MB <= gnO 5.2 MB

    auto gemm64 = [&](const ushort_t* A, const ushort_t* Wt, const float* bias,
                      const float* resid, float* Cf, ushort_t* Cb,
                      int M, int N, int K, float qsc = 1.f, int ncut = 0) {
        gemm_bf16_kernel<64><<<dim3(M / 64, N / 64), 256, 0, stream>>>(
            A, Wt, bias, resid, Cf, Cb, M, N, K, qsc, ncut);
    };
    auto gemm128 = [&](const ushort_t* A, const ushort_t* Wt, const float* bias,
                       const float* resid, float* Cf, ushort_t* Cb,
                       int M, int N, int K, float qsc = 1.f, int ncut = 0) {
        gemm_bf16_kernel<128><<<dim3(M / 128, N / 64), 256, 0, stream>>>(
            A, Wt, bias, resid, Cf, Cb, M, N, K, qsc, ncut);
    };

    // ---- fused weight prep (+ kv cvt + stats zero) ----
    {
        WTab tab;
        int t0 = 0;
        auto seg = [&](int i, const float* s, ushort_t* d, int K, int N) {
            tab.s[i] = {s, d, K, N, t0};
            t0 += (K / 32) * (N / 32);
        };
        seg(0,  cin_w,  cin_t,             320, 320);
        seg(1,  a1_wq,  qkv_t,             320, 320);
        seg(2,  a1_wk,  qkv_t + 320 * 320, 320, 320);
        seg(3,  a1_wv,  qkv_t + 640 * 320, 320, 320);
        seg(4,  a1_wo,  a1wo_t,            320, 320);
        seg(5,  a2_wq,  a2wq_t,            320, 320);
        seg(6,  a2_wk,  kvx_t,             768, 320);
        seg(7,  a2_wv,  kvx_t + 320 * 768, 768, 320);
        seg(8,  a2_wo,  a2wo_t,            320, 320);
        seg(9,  fc0_w,  fc0_t,             320, 2560);
        seg(10, fc1_w,  fc1_t,             1280, 320);
        seg(11, cout_w, cout_t,            320, 320);
        tab.cvt_src = kv; tab.cvt_dst = kvbf;
        tab.cvt_n = BATCH * KVL * KVD; tab.cvt_t0 = t0;
        tab.stats = stats;
        int ncvt_blk = (tab.cvt_n + 8191) / 8192;
        wtrans_all_kernel<<<t0 + ncvt_blk, 256, 0, stream>>>(tab);
    }

    // ---- GroupNorm + conv_in ----
    gn_partial_kernel<<<dim3(16, 64), 256, 0, stream>>>(q, stats);
    gn_apply_transpose_kernel<<<dim3(SPATIAL / 32, DIM / 32, BATCH), dim3(32, 32), 0, stream>>>(
        q, stats, gn_s, gn_b, gnO);
    gemm64(gnO, cin_t, cin_b, nullptr, B0, nullptr, ROWS, DIM, DIM);

    // ---- self-attention (split-K x4 flash, pre-transposed V) ----
    ln_kernel<<<ROWS / 4, 256, 0, stream>>>(B0, ln0_s, ln0_b, ln0O);
    gemm128(ln0O, qkv_t, nullptr, nullptr, nullptr, QKV, ROWS, 960, DIM, QK_EXP2_SCALE, 320);
    vtrans_kernel<<<dim3(SPATIAL / 32, 16), 256, 0, stream>>>(QKV, VTs, 960, 640, SPATIAL, SPATIAL);
    flash_kernel<SELF_PARTS><<<dim3(SPATIAL / TQ, NHEADS, BATCH * SELF_PARTS), 256, 0, stream>>>(
        QKV, QKV + 320, VTs, nullptr, Opart, Lpart, 960, 960, SPATIAL, SPATIAL);
    attn_merge_kernel<<<ROWS, 320, 0, stream>>>(Opart, Lpart, attnO);
    gemm64(attnO, a1wo_t, a1_bo, B0, B0, nullptr, ROWS, DIM, DIM);

    // ---- cross-attention ----
    ln_kernel<<<ROWS / 4, 256, 0, stream>>>(B0, ln1_s, ln1_b, ln1O);
    gemm64(ln1O, a2wq_t, nullptr, nullptr, nullptr, Q2, ROWS, DIM, DIM, QK_EXP2_SCALE, 320);
    gemm_small_kernel<<<dim3(3, 10), 256, 0, stream>>>(kvbf, kvx_t, KVc, BATCH * KVL, 640, KVD);
    vtrans_kernel<<<dim3(4, 16), 256, 0, stream>>>(KVc, VTc, 640, 320, KVL, 128);
    flash_kernel<1><<<dim3(SPATIAL / TQ, NHEADS, BATCH), 256, 0, stream>>>(
        Q2, KVc, VTc, attnO, nullptr, nullptr, 320, 640, 128, KVL);
    gemm64(attnO, a2wo_t, a2_bo, B0, B0, nullptr, ROWS, DIM, DIM);

    // ---- FFN (GEGLU) ----
    ln_kernel<<<ROWS / 4, 256, 0, stream>>>(B0, lnA_s, lnA_b, lnAO);
    geglu128_kernel<<<dim3(ROWS / 128, FF / 64), 256, 0, stream>>>(lnAO, fc0_t, fc0_b, GLU, ROWS);
    gemm64(GLU, fc1_t, fc1_b, B0, nullptr, X2, ROWS, DIM, FF);

    // ---- conv_out fused with NCHW transpose + res1 ----
    gemm_convout_kernel<<<dim3(ROWS / 64, DIM / 64), 256, 0, stream>>>(
        X2, cout_t, cout_b, q, out);
}

// Round 9
// 378.203 us; speedup vs baseline: 1.1560x; 1.1028x over previous
//
#include <hip/hip_runtime.h>
#include <math.h>

typedef short short8 __attribute__((ext_vector_type(8)));
typedef float floatx4 __attribute__((ext_vector_type(4)));
typedef unsigned short ushort_t;
typedef unsigned int uint_t;

// ---- problem constants ----
constexpr int BATCH   = 2;
constexpr int DIM     = 320;
constexpr int NHEADS  = 8;
constexpr int DH      = 40;
constexpr int NGROUPS = 32;
constexpr int CPG     = 10;
constexpr int SPATIAL = 4096;
constexpr int ROWS    = BATCH * SPATIAL;   // 8192
constexpr int KVL     = 77;
constexpr int KVD     = 768;
constexpr int FF      = 1280;              // geglu half width
constexpr int TQ      = 128;               // flash q-tile
constexpr int SELF_PARTS = 4;              // split-K parts for self-attn

// scale(1/sqrt(40)) * log2(e): folded into Q so flash uses exp2 directly
#define QK_EXP2_SCALE 0.2281259062f

__device__ __forceinline__ ushort_t f2bf(float f) {
    uint_t u = __float_as_uint(f);
    u += 0x7FFFu + ((u >> 16) & 1u);       // RNE
    return (ushort_t)(u >> 16);
}
__device__ __forceinline__ float bf2f(ushort_t u) {
    return __uint_as_float(((uint_t)u) << 16);
}

// async global->LDS, 16B per lane; LDS dest = wave-uniform base + lane*16
__device__ __forceinline__ void gld16(const ushort_t* g, ushort_t* l) {
    __builtin_amdgcn_global_load_lds(
        (const __attribute__((address_space(1))) void*)g,
        (__attribute__((address_space(3))) void*)l, 16, 0, 0);
}

// ---------------------------------------------------------------------------
// GroupNorm partial sums: grid (16 slices, 64 groups), atomics into stats.
// ---------------------------------------------------------------------------
__global__ __launch_bounds__(256) void gn_partial_kernel(const float* __restrict__ q,
                                                         float* __restrict__ stats) {
    int slice = blockIdx.x, bg = blockIdx.y;
    const float* base = q + (size_t)bg * (CPG * SPATIAL) + slice * 2560;
    float s = 0.f, ss = 0.f;
#pragma unroll
    for (int j = 0; j < 10; j++) {
        float v = base[j * 256 + threadIdx.x];
        s += v; ss += v * v;
    }
    __shared__ float rs[256], rss[256];
    rs[threadIdx.x] = s; rss[threadIdx.x] = ss;
    __syncthreads();
    for (int off = 128; off > 0; off >>= 1) {
        if (threadIdx.x < off) {
            rs[threadIdx.x]  += rs[threadIdx.x + off];
            rss[threadIdx.x] += rss[threadIdx.x + off];
        }
        __syncthreads();
    }
    if (threadIdx.x == 0) {
        atomicAdd(&stats[bg * 2],     rs[0]);
        atomicAdd(&stats[bg * 2 + 1], rss[0]);
    }
}

__global__ void gn_apply_transpose_kernel(const float* __restrict__ q,
                                          const float* __restrict__ stats,
                                          const float* __restrict__ gs,
                                          const float* __restrict__ gb,
                                          ushort_t* __restrict__ out) {
    __shared__ float tile[32][33];
    int l0 = blockIdx.x * 32, c0 = blockIdx.y * 32, b = blockIdx.z;
    int tx = threadIdx.x, ty = threadIdx.y;
    int c = c0 + ty;
    int g = c / CPG;
    float s  = stats[(b * NGROUPS + g) * 2];
    float ss = stats[(b * NGROUPS + g) * 2 + 1];
    const float invn = 1.f / 40960.f;
    float mean = s * invn;
    float rstd = rsqrtf(ss * invn - mean * mean + 1e-6f);
    float v = q[((size_t)(b * DIM + c)) * SPATIAL + l0 + tx];
    tile[ty][tx] = (v - mean) * rstd * gs[c] + gb[c];
    __syncthreads();
    out[((size_t)(b * SPATIAL + l0 + ty)) * DIM + c0 + tx] = f2bf(tile[tx][ty]);
}

// ---------------------------------------------------------------------------
// LayerNorm rows of 320, f32 in, bf16 out. 4 rows per 256-thread block.
// ---------------------------------------------------------------------------
__global__ __launch_bounds__(256) void ln_kernel(const float* __restrict__ x,
                                                 const float* __restrict__ sc,
                                                 const float* __restrict__ bi,
                                                 ushort_t* __restrict__ out) {
    int row = blockIdx.x * 4 + (threadIdx.x >> 6);
    int lane = threadIdx.x & 63;
    const float* xr = x + (size_t)row * DIM;
    float v[5];
    float sum = 0.f, sq = 0.f;
#pragma unroll
    for (int j = 0; j < 5; j++) {
        v[j] = xr[lane + j * 64];
        sum += v[j]; sq += v[j] * v[j];
    }
#pragma unroll
    for (int off = 32; off > 0; off >>= 1) {
        sum += __shfl_down(sum, off);
        sq  += __shfl_down(sq, off);
    }
    sum = __shfl(sum, 0); sq = __shfl(sq, 0);
    float mean = sum / (float)DIM;
    float rstd = rsqrtf(sq / (float)DIM - mean * mean + 1e-5f);
#pragma unroll
    for (int j = 0; j < 5; j++) {
        int i = lane + j * 64;
        out[(size_t)row * DIM + i] = f2bf((v[j] - mean) * rstd * sc[i] + bi[i]);
    }
}

// ---------------------------------------------------------------------------
// Weight prep fused: 12 transpose segments (f32 [K][N] -> bf16 [N][K]) +
// kv f32->bf16 convert + stats zero, all in one launch.
// ---------------------------------------------------------------------------
struct WSeg { const float* src; ushort_t* dst; int K; int N; int t0; };
struct WTab {
    WSeg s[12];
    const float* cvt_src; ushort_t* cvt_dst; int cvt_n; int cvt_t0;
    float* stats;
};

__global__ __launch_bounds__(256) void wtrans_all_kernel(WTab tab) {
    int bid = blockIdx.x;
    if (bid >= tab.cvt_t0) {
        int local = bid - tab.cvt_t0;
        int base = local * 8192;
#pragma unroll
        for (int j = 0; j < 32; j++) {
            int i = base + j * 256 + threadIdx.x;
            if (i < tab.cvt_n) tab.cvt_dst[i] = f2bf(tab.cvt_src[i]);
        }
        if (local == 0 && threadIdx.x < 128) tab.stats[threadIdx.x] = 0.f;
        return;
    }
    __shared__ float tile[32][33];
    int si = 0;
#pragma unroll
    for (int i = 1; i < 12; i++) if (bid >= tab.s[i].t0) si = i;
    WSeg sg = tab.s[si];
    int local = bid - sg.t0;
    int ntn = sg.N >> 5;
    int kt = local / ntn, nt = local - kt * ntn;
    int n0 = nt * 32, k0 = kt * 32;
    int tx = threadIdx.x & 31, ty8 = threadIdx.x >> 5;
    for (int r = ty8; r < 32; r += 8)
        tile[r][tx] = sg.src[(size_t)(k0 + r) * sg.N + n0 + tx];
    __syncthreads();
    for (int r = ty8; r < 32; r += 8)
        sg.dst[(size_t)(n0 + r) * sg.K + k0 + tx] = f2bf(tile[tx][r]);
}

// ---------------------------------------------------------------------------
// V pre-transpose: src rows [b*L + l][stride] head cols -> VT[bh][48][Lpad].
// Row 40 = ones (bf16 1.0), rows 41..47 = 0; padded keys zeroed.
// ---------------------------------------------------------------------------
__global__ __launch_bounds__(256) void vtrans_kernel(const ushort_t* __restrict__ src,
                                                     ushort_t* __restrict__ dst,
                                                     int stride, int headOff,
                                                     int L, int Lpad) {
    __shared__ ushort_t tile[32][41];
    int bh = blockIdx.y, b = bh >> 3, h = bh & 7;
    int l0 = blockIdx.x * 32;
    for (int idx = threadIdx.x; idx < 32 * 40; idx += 256) {
        int l = idx / 40, d = idx - l * 40;
        ushort_t v = 0;
        if (l0 + l < L)
            v = src[(size_t)(b * L + l0 + l) * stride + headOff + h * DH + d];
        tile[l][d] = v;
    }
    __syncthreads();
    for (int idx = threadIdx.x; idx < 48 * 32; idx += 256) {
        int d = idx >> 5, li = idx & 31;
        ushort_t v;
        if (d < 40)      v = tile[li][d];
        else if (d == 40) v = 0x3F80;     // bf16 1.0 (ones column for row-sum)
        else             v = 0;
        dst[((size_t)bh * 48 + d) * Lpad + l0 + li] = v;
    }
}

// ---------------------------------------------------------------------------
// bf16 MFMA GEMM, templated M-tile (64 or 128) x 64(N) x 64(K) steps.
// global_load_lds + XOR-swizzled unpadded LDS.
// ---------------------------------------------------------------------------
template <int TM>
__global__ __launch_bounds__(256) void gemm_bf16_kernel(
    const ushort_t* __restrict__ A, const ushort_t* __restrict__ Wt,
    const float* __restrict__ bias, const float* __restrict__ resid,
    float* __restrict__ Cf, ushort_t* __restrict__ Cb,
    int M, int N, int K, float qsc, int ncut)
{
    constexpr int G = TM / 64;          // row-groups per wave
    __shared__ __align__(16) ushort_t As[TM][64];
    __shared__ __align__(16) ushort_t Bs[64][64];
    int tid = threadIdx.x;
    int wave = tid >> 6, lane = tid & 63;
    int l15 = tid & 15, quad = lane >> 4;
    int m0 = blockIdx.x * TM, n0 = blockIdx.y * 64;
    int lrow = lane >> 3, slot = lane & 7;
    floatx4 acc[G][4] = {};

    for (int k0 = 0; k0 < K; k0 += 64) {
#pragma unroll
        for (int t = 0; t < TM / 32; t++) {
            int task = wave * (TM / 32) + t;
            int r = task * 8 + lrow;
            int gc = slot ^ (r & 7);
            gld16(&A[(size_t)(m0 + r) * K + k0 + gc * 8], &As[task * 8][0]);
        }
#pragma unroll
        for (int t = 0; t < 2; t++) {
            int task = wave * 2 + t;
            int r = task * 8 + lrow;
            int gc = slot ^ (r & 7);
            gld16(&Wt[(size_t)(n0 + r) * K + k0 + gc * 8], &Bs[task * 8][0]);
        }
        __syncthreads();
        short8 a[G][2], b[4][2];
#pragma unroll
        for (int g = 0; g < G; g++) {
            int r = (TM / 4) * wave + 16 * g + l15;
            a[g][0] = *(const short8*)&As[r][(quad ^ (r & 7)) * 8];
            a[g][1] = *(const short8*)&As[r][((4 + quad) ^ (r & 7)) * 8];
        }
#pragma unroll
        for (int t = 0; t < 4; t++) {
            int r = 16 * t + l15;
            b[t][0] = *(const short8*)&Bs[r][(quad ^ (r & 7)) * 8];
            b[t][1] = *(const short8*)&Bs[r][((4 + quad) ^ (r & 7)) * 8];
        }
#pragma unroll
        for (int g = 0; g < G; g++)
#pragma unroll
            for (int t = 0; t < 4; t++) {
                acc[g][t] = __builtin_amdgcn_mfma_f32_16x16x32_bf16(a[g][0], b[t][0], acc[g][t], 0, 0, 0);
                acc[g][t] = __builtin_amdgcn_mfma_f32_16x16x32_bf16(a[g][1], b[t][1], acc[g][t], 0, 0, 0);
            }
        __syncthreads();
    }

#pragma unroll
    for (int g = 0; g < G; g++) {
        int mrow = m0 + (TM / 4) * wave + 16 * g + quad * 4;
#pragma unroll
        for (int t = 0; t < 4; t++) {
            int n = n0 + 16 * t + l15;
            float bv = bias ? bias[n] : 0.f;
            float sc = (n < ncut) ? qsc : 1.f;
#pragma unroll
            for (int i = 0; i < 4; i++) {
                int m = mrow + i;
                float v = acc[g][t][i] + bv;
                if (resid) v += resid[(size_t)m * N + n];
                v *= sc;
                if (Cf) Cf[(size_t)m * N + n] = v;
                if (Cb) Cb[(size_t)m * N + n] = f2bf(v);
            }
        }
    }
}

// ---------------------------------------------------------------------------
// fc0+GEGLU on the 128-tile structure: dual B (value n0.., gate FF+n0..)
// ---------------------------------------------------------------------------
__global__ __launch_bounds__(256) void geglu128_kernel(
    const ushort_t* __restrict__ A, const ushort_t* __restrict__ Wt,
    const float* __restrict__ bias, ushort_t* __restrict__ C, int M)
{
    constexpr int K = 320;
    __shared__ __align__(16) ushort_t As[128][64];
    __shared__ __align__(16) ushort_t Bv[64][64];
    __shared__ __align__(16) ushort_t Bg[64][64];
    int tid = threadIdx.x;
    int wave = tid >> 6, lane = tid & 63;
    int l15 = tid & 15, quad = lane >> 4;
    int m0 = blockIdx.x * 128, n0 = blockIdx.y * 64;
    int lrow = lane >> 3, slot = lane & 7;
    floatx4 av[2][4] = {}, ag[2][4] = {};

    for (int k0 = 0; k0 < K; k0 += 64) {
#pragma unroll
        for (int t = 0; t < 4; t++) {
            int task = wave * 4 + t;
            int r = task * 8 + lrow;
            int gc = slot ^ (r & 7);
            gld16(&A[(size_t)(m0 + r) * K + k0 + gc * 8], &As[task * 8][0]);
        }
#pragma unroll
        for (int t = 0; t < 2; t++) {
            int task = wave * 2 + t;
            int r = task * 8 + lrow;
            int gc = slot ^ (r & 7);
            gld16(&Wt[(size_t)(n0 + r) * K + k0 + gc * 8],      &Bv[task * 8][0]);
            gld16(&Wt[(size_t)(FF + n0 + r) * K + k0 + gc * 8], &Bg[task * 8][0]);
        }
        __syncthreads();
        short8 a[2][2], bv[4][2], bg[4][2];
#pragma unroll
        for (int g = 0; g < 2; g++) {
            int r = 32 * wave + 16 * g + l15;
            a[g][0] = *(const short8*)&As[r][(quad ^ (r & 7)) * 8];
            a[g][1] = *(const short8*)&As[r][((4 + quad) ^ (r & 7)) * 8];
        }
#pragma unroll
        for (int t = 0; t < 4; t++) {
            int r = 16 * t + l15;
            bv[t][0] = *(const short8*)&Bv[r][(quad ^ (r & 7)) * 8];
            bv[t][1] = *(const short8*)&Bv[r][((4 + quad) ^ (r & 7)) * 8];
            bg[t][0] = *(const short8*)&Bg[r][(quad ^ (r & 7)) * 8];
            bg[t][1] = *(const short8*)&Bg[r][((4 + quad) ^ (r & 7)) * 8];
        }
#pragma unroll
        for (int g = 0; g < 2; g++)
#pragma unroll
            for (int t = 0; t < 4; t++) {
                av[g][t] = __builtin_amdgcn_mfma_f32_16x16x32_bf16(a[g][0], bv[t][0], av[g][t], 0, 0, 0);
                av[g][t] = __builtin_amdgcn_mfma_f32_16x16x32_bf16(a[g][1], bv[t][1], av[g][t], 0, 0, 0);
                ag[g][t] = __builtin_amdgcn_mfma_f32_16x16x32_bf16(a[g][0], bg[t][0], ag[g][t], 0, 0, 0);
                ag[g][t] = __builtin_amdgcn_mfma_f32_16x16x32_bf16(a[g][1], bg[t][1], ag[g][t], 0, 0, 0);
            }
        __syncthreads();
    }

#pragma unroll
    for (int g = 0; g < 2; g++) {
        int mrow = m0 + 32 * wave + 16 * g + quad * 4;
#pragma unroll
        for (int t = 0; t < 4; t++) {
            int n = n0 + 16 * t + l15;
            float bb = bias[n], bgte = bias[FF + n];
#pragma unroll
            for (int i = 0; i < 4; i++) {
                float val  = av[g][t][i] + bb;
                float gate = ag[g][t][i] + bgte;
                float gl = 0.5f * gate * (1.f + erff(gate * 0.70710678118654752f));
                C[(size_t)(mrow + i) * FF + n] = f2bf(val * gl);
            }
        }
    }
}

// ---------------------------------------------------------------------------
// conv_out fused with NCHW transpose + res1.
// ---------------------------------------------------------------------------
__global__ __launch_bounds__(256) void gemm_convout_kernel(
    const ushort_t* __restrict__ A, const ushort_t* __restrict__ Wt,
    const float* __restrict__ bias, const float* __restrict__ qres,
    float* __restrict__ out)
{
    constexpr int K = 320;
    __shared__ __align__(16) ushort_t As[64][64];
    __shared__ __align__(16) ushort_t Bs[64][64];
    __shared__ float Cf[64][68];
    int tid = threadIdx.x;
    int wave = tid >> 6, lane = tid & 63;
    int l15 = tid & 15, quad = lane >> 4;
    int m0 = blockIdx.x * 64, n0 = blockIdx.y * 64;
    int lrow = lane >> 3, slot = lane & 7;
    floatx4 acc[4] = {};

    for (int k0 = 0; k0 < K; k0 += 64) {
#pragma unroll
        for (int t = 0; t < 2; t++) {
            int task = wave * 2 + t;
            int r = task * 8 + lrow;
            int gc = slot ^ (r & 7);
            gld16(&A[(size_t)(m0 + r) * K + k0 + gc * 8], &As[task * 8][0]);
            gld16(&Wt[(size_t)(n0 + r) * K + k0 + gc * 8], &Bs[task * 8][0]);
        }
        __syncthreads();
        short8 a0, a1, b[4][2];
        {
            int r = 16 * wave + l15;
            a0 = *(const short8*)&As[r][(quad ^ (r & 7)) * 8];
            a1 = *(const short8*)&As[r][((4 + quad) ^ (r & 7)) * 8];
        }
#pragma unroll
        for (int t = 0; t < 4; t++) {
            int r = 16 * t + l15;
            b[t][0] = *(const short8*)&Bs[r][(quad ^ (r & 7)) * 8];
            b[t][1] = *(const short8*)&Bs[r][((4 + quad) ^ (r & 7)) * 8];
        }
#pragma unroll
        for (int t = 0; t < 4; t++) {
            acc[t] = __builtin_amdgcn_mfma_f32_16x16x32_bf16(a0, b[t][0], acc[t], 0, 0, 0);
            acc[t] = __builtin_amdgcn_mfma_f32_16x16x32_bf16(a1, b[t][1], acc[t], 0, 0, 0);
        }
        __syncthreads();
    }

#pragma unroll
    for (int t = 0; t < 4; t++) {
        int n = 16 * t + l15;
        float bv = bias[n0 + n];
        int mbase = 16 * wave + 4 * quad;
#pragma unroll
        for (int i = 0; i < 4; i++)
            Cf[n][mbase + i] = acc[t][i] + bv;
    }
    __syncthreads();
    {
        int n = tid >> 2, j = tid & 3;
        int bq = m0 >> 12;
        int l0 = m0 & 4095;
        size_t goff = ((size_t)(bq * DIM + n0 + n)) * SPATIAL + l0 + j * 16;
        const float4* qr = (const float4*)(qres + goff);
        float4* op = (float4*)(out + goff);
#pragma unroll
        for (int c = 0; c < 4; c++) {
            float4 v = *(const float4*)&Cf[n][j * 16 + c * 4];
            float4 qv = qr[c];
            v.x += qv.x; v.y += qv.y; v.z += qv.z; v.w += qv.w;
            op[c] = v;
        }
    }
}

// ---------------------------------------------------------------------------
// Small-M bf16 GEMM (cross K/V projection, M=154).
// ---------------------------------------------------------------------------
__global__ __launch_bounds__(256) void gemm_small_kernel(
    const ushort_t* __restrict__ A, const ushort_t* __restrict__ Wt,
    ushort_t* __restrict__ Cb, int M, int N, int K)
{
    __shared__ __align__(16) ushort_t As[64][72];
    __shared__ __align__(16) ushort_t Bs[64][72];
    int tid = threadIdx.x;
    int wave = tid >> 6, l15 = tid & 15, quad = (tid & 63) >> 4;
    int m0 = blockIdx.x * 64, n0 = blockIdx.y * 64;
    floatx4 acc[4] = {};

    for (int k0 = 0; k0 < K; k0 += 64) {
#pragma unroll
        for (int p = 0; p < 2; p++) {
            int lin = p * 256 + tid;
            int r = lin >> 3, c8 = (lin & 7) * 8;
            int m = m0 + r;
            short8 avv = {};
            if (m < M) avv = *(const short8*)&A[(size_t)m * K + k0 + c8];
            *(short8*)&As[r][c8] = avv;
            *(short8*)&Bs[r][c8] = *(const short8*)&Wt[(size_t)(n0 + r) * K + k0 + c8];
        }
        __syncthreads();
        short8 a0 = *(const short8*)&As[16 * wave + l15][quad * 8];
        short8 a1 = *(const short8*)&As[16 * wave + l15][32 + quad * 8];
#pragma unroll
        for (int t = 0; t < 4; t++) {
            short8 b0 = *(const short8*)&Bs[16 * t + l15][quad * 8];
            short8 b1 = *(const short8*)&Bs[16 * t + l15][32 + quad * 8];
            acc[t] = __builtin_amdgcn_mfma_f32_16x16x32_bf16(a0, b0, acc[t], 0, 0, 0);
            acc[t] = __builtin_amdgcn_mfma_f32_16x16x32_bf16(a1, b1, acc[t], 0, 0, 0);
        }
        __syncthreads();
    }
    int mrow = m0 + 16 * wave + quad * 4;
#pragma unroll
    for (int t = 0; t < 4; t++) {
        int n = n0 + 16 * t + l15;
#pragma unroll
        for (int i = 0; i < 4; i++) {
            int m = mrow + i;
            if (m < M) Cb[(size_t)m * N + n] = f2bf(acc[t][i]);
        }
    }
}

// ---------------------------------------------------------------------------
// Flash attention v5: VALU-lean softmax. Changes vs v4.2:
//  - raw __builtin_amdgcn_exp2f (no libm fixup code)
//  - P layout de-swizzled to canonical chunk-major QPs[col/8][row][col%8]:
//    bank math shows <=2-way (free) for both b16 scatter and b128 frag reads,
//    and all P addresses become compile-time offsets from one per-lane base.
//  - FULL template: self-attn (nk % 64 == 0 per part) drops per-element masks.
// ---------------------------------------------------------------------------
template <int NPARTS, bool FULL>
__global__ __launch_bounds__(256) void flash_kernel(
    const ushort_t* __restrict__ Qg, const ushort_t* __restrict__ Kg,
    const ushort_t* __restrict__ VT, ushort_t* __restrict__ Og,
    ushort_t* __restrict__ Opart, float* __restrict__ Lpart,
    int sQ, int sKV, int Lpad, int nk)
{
    __shared__ __align__(16) ushort_t QPs[8][130][8];   // Q rows 0..127, then P
    __shared__ __align__(16) ushort_t Ks[8][64][8];
    __shared__ __align__(16) ushort_t VsT[48][64];      // [dh][key], key-chunks XOR-swizzled

    int tid = threadIdx.x;
    int wave = tid >> 6, lane = tid & 63;
    int l15 = tid & 15, quad = lane >> 4;
    int qt = blockIdx.x, h = blockIdx.y;
    int b, kp;
    if (NPARTS > 1) { b = blockIdx.z / NPARTS; kp = blockIdx.z % NPARTS; }
    else            { b = blockIdx.z;          kp = 0; }
    int q0 = qt * TQ;

    const ushort_t* Qb  = Qg + (size_t)(b * SPATIAL + q0) * sQ + h * DH;
    const ushort_t* Kb  = Kg + (size_t)b * nk * sKV + h * DH;
    const ushort_t* VTb = VT + (size_t)(b * NHEADS + h) * 48 * Lpad;

    // zero pad chunks ONCE: Ks 5..7 AND QPs 5..7 (NaN fix: aq[g][1] reads
    // QPs planes 4..7; stale LDS f32 data can alias bf16 NaN -> 0*NaN=NaN)
    const short8 z8 = {};
    for (int i = tid; i < 3 * 64; i += 256)
        *(short8*)&Ks[5 + (i >> 6)][i & 63][0] = z8;
    for (int i = tid; i < 3 * 130; i += 256)
        *(short8*)&QPs[5 + i / 130][i % 130][0] = z8;

    // stage Q: 10 wave-tasks of 64 rows x 16B
    for (int t5 = wave; t5 < 10; t5 += 4) {
        int cid = t5 >> 1, half = t5 & 1;
        gld16(&Qb[(size_t)(half * 64 + lane) * sQ + cid * 8], &QPs[cid][half * 64][0]);
    }
    __syncthreads();

    short8 aq[2][2];
#pragma unroll
    for (int g = 0; g < 2; g++) {
        int r = 32 * wave + 16 * g + l15;
        aq[g][0] = *(const short8*)&QPs[quad][r][0];
        aq[g][1] = *(const short8*)&QPs[4 + quad][r][0];
    }

    // tile-invariant P pointers (element strides: plane=1040, row=8)
    // write: P[row=32w+16g+4q+i][col=16tt+l15] -> QPs[col/8][row][col%8]
    ushort_t* pw = &QPs[l15 >> 3][32 * wave + 4 * quad][l15 & 7];
    const ushort_t* pr = &QPs[quad][32 * wave + l15][0];

    floatx4 o[2][3] = {};

    int ntiles_all = (nk + 63) >> 6;
    int per = ntiles_all / NPARTS;
    int t_lo = kp * per;
    int t_hi = (NPARTS > 1) ? t_lo + per : ntiles_all;

    for (int t = t_lo; t < t_hi; t++) {
        int k0 = t * 64;
        __syncthreads();
        for (int c = wave; c < 5; c += 4)
            gld16(&Kb[(size_t)(k0 + lane) * sKV + c * 8], &Ks[c][0][0]);
        for (int c = wave; c < 6; c += 4) {
            int r8 = lane >> 3;
            int gc = (lane & 7) ^ r8;
            gld16(&VTb[(size_t)(c * 8 + r8) * Lpad + k0 + gc * 8], &VsT[c * 8][0]);
        }
        __syncthreads();

        // S' = (Q*scale*log2e) K^T
        floatx4 s[2][4] = {};
#pragma unroll
        for (int tt = 0; tt < 4; tt++) {
            short8 b0 = *(const short8*)&Ks[quad][16 * tt + l15][0];
            short8 b1 = *(const short8*)&Ks[4 + quad][16 * tt + l15][0];
#pragma unroll
            for (int g = 0; g < 2; g++) {
                s[g][tt] = __builtin_amdgcn_mfma_f32_16x16x32_bf16(aq[g][0], b0, s[g][tt], 0, 0, 0);
                s[g][tt] = __builtin_amdgcn_mfma_f32_16x16x32_bf16(aq[g][1], b1, s[g][tt], 0, 0, 0);
            }
        }

        // p = exp2(s'), trunc-bf16, compile-time-offset scatter
#pragma unroll
        for (int g = 0; g < 2; g++) {
#pragma unroll
            for (int i = 0; i < 4; i++) {
#pragma unroll
                for (int tt = 0; tt < 4; tt++) {
                    float x = s[g][tt][i];
                    if (!FULL && (k0 + 16 * tt + l15 >= nk)) x = -1e30f;
                    float pf = __builtin_amdgcn_exp2f(x);
                    pw[tt * 2080 + g * 128 + i * 8] =
                        (ushort_t)(__float_as_uint(pf) >> 16);
                }
            }
        }

        // O += P @ [V | 1]; col 40 accumulates l. P rows wave-private.
        short8 vb[3][2];
#pragma unroll
        for (int t2 = 0; t2 < 3; t2++) {
            int R = 16 * t2 + l15;
            vb[t2][0] = *(const short8*)&VsT[R][(quad ^ (l15 & 7)) * 8];
            vb[t2][1] = *(const short8*)&VsT[R][((4 + quad) ^ (l15 & 7)) * 8];
        }
#pragma unroll
        for (int g = 0; g < 2; g++) {
            short8 p0 = *(const short8*)(pr + g * 128);
            short8 p1 = *(const short8*)(pr + 4 * 1040 + g * 128);
#pragma unroll
            for (int t2 = 0; t2 < 3; t2++) {
                o[g][t2] = __builtin_amdgcn_mfma_f32_16x16x32_bf16(p0, vb[t2][0], o[g][t2], 0, 0, 0);
                o[g][t2] = __builtin_amdgcn_mfma_f32_16x16x32_bf16(p1, vb[t2][1], o[g][t2], 0, 0, 0);
            }
        }
    }

    if (NPARTS == 1) {
        float inv[2][4];
#pragma unroll
        for (int g = 0; g < 2; g++)
#pragma unroll
            for (int i = 0; i < 4; i++)
                inv[g][i] = 1.f / __shfl(o[g][2][i], (lane & 48) | 8, 64);
#pragma unroll
        for (int g = 0; g < 2; g++)
#pragma unroll
            for (int t2 = 0; t2 < 3; t2++) {
                int c = 16 * t2 + l15;
                if (c < DH) {
#pragma unroll
                    for (int i = 0; i < 4; i++) {
                        size_t row = (size_t)(b * SPATIAL + q0 + 32 * wave + 16 * g + 4 * quad + i);
                        Og[row * DIM + h * DH + c] = f2bf(o[g][t2][i] * inv[g][i]);
                    }
                }
            }
    } else {
        // bf16 partials (error budget: ~0.4% rel per part, absmax stays << 0.1)
#pragma unroll
        for (int g = 0; g < 2; g++) {
#pragma unroll
            for (int t2 = 0; t2 < 3; t2++) {
                int c = 16 * t2 + l15;
                if (c < DH) {
#pragma unroll
                    for (int i = 0; i < 4; i++) {
                        size_t row = (size_t)(b * SPATIAL + q0 + 32 * wave + 16 * g + 4 * quad + i);
                        Opart[((size_t)kp * ROWS + row) * DIM + h * DH + c] = f2bf(o[g][t2][i]);
                    }
                }
            }
            if (l15 == 8) {
#pragma unroll
                for (int i = 0; i < 4; i++) {
                    size_t row = (size_t)(b * SPATIAL + q0 + 32 * wave + 16 * g + 4 * quad + i);
                    Lpart[((size_t)kp * ROWS + row) * NHEADS + h] = o[g][2][i];
                }
            }
        }
    }
}

// merge split-K partials: out = (Σ o_kp) / (Σ l_kp), bf16 partials
__global__ __launch_bounds__(320) void attn_merge_kernel(
    const ushort_t* __restrict__ Op, const float* __restrict__ Lp,
    ushort_t* __restrict__ Og)
{
    int row = blockIdx.x, c = threadIdx.x;
    int h = c / DH;
    float l = 0.f, o = 0.f;
#pragma unroll
    for (int kp = 0; kp < SELF_PARTS; kp++) {
        l += Lp[((size_t)kp * ROWS + row) * NHEADS + h];
        o += bf2f(Op[((size_t)kp * ROWS + row) * DIM + c]);
    }
    Og[(size_t)row * DIM + c] = f2bf(o / l);
}

// ---------------------------------------------------------------------------
extern "C" void kernel_launch(void* const* d_in, const int* in_sizes, int n_in,
                              void* d_out, int out_size, void* d_ws, size_t ws_size,
                              hipStream_t stream) {
    (void)in_sizes; (void)n_in; (void)out_size; (void)ws_size;
    const float* q      = (const float*)d_in[0];
    const float* kv     = (const float*)d_in[1];
    const float* gn_s   = (const float*)d_in[2];
    const float* gn_b   = (const float*)d_in[3];
    const float* cin_w  = (const float*)d_in[4];
    const float* cin_b  = (const float*)d_in[5];
    const float* ln0_s  = (const float*)d_in[6];
    const float* ln0_b  = (const float*)d_in[7];
    const float* a1_wq  = (const float*)d_in[8];
    const float* a1_wk  = (const float*)d_in[9];
    const float* a1_wv  = (const float*)d_in[10];
    const float* a1_wo  = (const float*)d_in[11];
    const float* a1_bo  = (const float*)d_in[12];
    const float* ln1_s  = (const float*)d_in[13];
    const float* ln1_b  = (const float*)d_in[14];
    const float* a2_wq  = (const float*)d_in[15];
    const float* a2_wk  = (const float*)d_in[16];
    const float* a2_wv  = (const float*)d_in[17];
    const float* a2_wo  = (const float*)d_in[18];
    const float* a2_bo  = (const float*)d_in[19];
    const float* lnA_s  = (const float*)d_in[20];
    const float* lnA_b  = (const float*)d_in[21];
    const float* fc0_w  = (const float*)d_in[22];
    const float* fc0_b  = (const float*)d_in[23];
    const float* fc1_w  = (const float*)d_in[24];
    const float* fc1_b  = (const float*)d_in[25];
    const float* cout_w = (const float*)d_in[26];
    const float* cout_b = (const float*)d_in[27];
    float* out = (float*)d_out;

    // ---- workspace carve ----
    char* p = (char*)d_ws;
    auto carve = [&](size_t bytes) -> char* {
        char* r = p;
        p += (bytes + 255) & ~(size_t)255;
        return r;
    };
    float*    stats  = (float*)carve(512);
    float*    B0     = (float*)carve((size_t)ROWS * DIM * 4);
    ushort_t* gnO    = (ushort_t*)carve((size_t)ROWS * DIM * 2);
    ushort_t* ln0O   = (ushort_t*)carve((size_t)ROWS * DIM * 2);
    ushort_t* QKV    = (ushort_t*)carve((size_t)ROWS * 960 * 2);
    ushort_t* attnO  = (ushort_t*)carve((size_t)ROWS * DIM * 2);
    ushort_t* ln1O   = (ushort_t*)carve((size_t)ROWS * DIM * 2);
    ushort_t* Q2     = (ushort_t*)carve((size_t)ROWS * DIM * 2);
    ushort_t* KVc    = (ushort_t*)carve((size_t)BATCH * KVL * 640 * 2);
    ushort_t* lnAO   = (ushort_t*)carve((size_t)ROWS * DIM * 2);
    ushort_t* GLU    = (ushort_t*)carve((size_t)ROWS * FF * 2);
    ushort_t* X2     = (ushort_t*)carve((size_t)ROWS * DIM * 2);
    ushort_t* kvbf   = (ushort_t*)carve((size_t)BATCH * KVL * KVD * 2);
    ushort_t* VTs    = (ushort_t*)carve((size_t)16 * 48 * SPATIAL * 2);  // self V^T
    ushort_t* VTc    = (ushort_t*)carve((size_t)16 * 48 * 128 * 2);      // cross V^T
    ushort_t* qkv_t  = (ushort_t*)carve((size_t)960 * 320 * 2);
    ushort_t* cin_t  = (ushort_t*)carve((size_t)320 * 320 * 2);
    ushort_t* a1wo_t = (ushort_t*)carve((size_t)320 * 320 * 2);
    ushort_t* a2wq_t = (ushort_t*)carve((size_t)320 * 320 * 2);
    ushort_t* kvx_t  = (ushort_t*)carve((size_t)640 * 768 * 2);
    ushort_t* a2wo_t = (ushort_t*)carve((size_t)320 * 320 * 2);
    ushort_t* fc0_t  = (ushort_t*)carve((size_t)2560 * 320 * 2);
    ushort_t* fc1_t  = (ushort_t*)carve((size_t)320 * 1280 * 2);
    ushort_t* cout_t = (ushort_t*)carve((size_t)320 * 320 * 2);
    // split-K partials alias phase-disjoint buffers:
    ushort_t* Opart = GLU;           // 4 * ROWS * DIM * 2 B = 21.0 MB == GLU
    float*    Lpart = (float*)gnO;   // 4 * ROWS * 8 f32 = 1.05 MB <= gnO 5.2 MB

    auto gemm64 = [&](const ushort_t* A, const ushort_t* Wt, const float* bias,
                      const float* resid, float* Cf, ushort_t* Cb,
                      int M, int N, int K, float qsc = 1.f, int ncut = 0) {
        gemm_bf16_kernel<64><<<dim3(M / 64, N / 64), 256, 0, stream>>>(
            A, Wt, bias, resid, Cf, Cb, M, N, K, qsc, ncut);
    };
    auto gemm128 = [&](const ushort_t* A, const ushort_t* Wt, const float* bias,
                       const float* resid, float* Cf, ushort_t* Cb,
                       int M, int N, int K, float qsc = 1.f, int ncut = 0) {
        gemm_bf16_kernel<128><<<dim3(M / 128, N / 64), 256, 0, stream>>>(
            A, Wt, bias, resid, Cf, Cb, M, N, K, qsc, ncut);
    };

    // ---- fused weight prep (+ kv cvt + stats zero) ----
    {
        WTab tab;
        int t0 = 0;
        auto seg = [&](int i, const float* s, ushort_t* d, int K, int N) {
            tab.s[i] = {s, d, K, N, t0};
            t0 += (K / 32) * (N / 32);
        };
        seg(0,  cin_w,  cin_t,             320, 320);
        seg(1,  a1_wq,  qkv_t,             320, 320);
        seg(2,  a1_wk,  qkv_t + 320 * 320, 320, 320);
        seg(3,  a1_wv,  qkv_t + 640 * 320, 320, 320);
        seg(4,  a1_wo,  a1wo_t,            320, 320);
        seg(5,  a2_wq,  a2wq_t,            320, 320);
        seg(6,  a2_wk,  kvx_t,             768, 320);
        seg(7,  a2_wv,  kvx_t + 320 * 768, 768, 320);
        seg(8,  a2_wo,  a2wo_t,            320, 320);
        seg(9,  fc0_w,  fc0_t,             320, 2560);
        seg(10, fc1_w,  fc1_t,             1280, 320);
        seg(11, cout_w, cout_t,            320, 320);
        tab.cvt_src = kv; tab.cvt_dst = kvbf;
        tab.cvt_n = BATCH * KVL * KVD; tab.cvt_t0 = t0;
        tab.stats = stats;
        int ncvt_blk = (tab.cvt_n + 8191) / 8192;
        wtrans_all_kernel<<<t0 + ncvt_blk, 256, 0, stream>>>(tab);
    }

    // ---- GroupNorm + conv_in ----
    gn_partial_kernel<<<dim3(16, 64), 256, 0, stream>>>(q, stats);
    gn_apply_transpose_kernel<<<dim3(SPATIAL / 32, DIM / 32, BATCH), dim3(32, 32), 0, stream>>>(
        q, stats, gn_s, gn_b, gnO);
    gemm64(gnO, cin_t, cin_b, nullptr, B0, nullptr, ROWS, DIM, DIM);

    // ---- self-attention (split-K x4 flash, pre-transposed V) ----
    ln_kernel<<<ROWS / 4, 256, 0, stream>>>(B0, ln0_s, ln0_b, ln0O);
    gemm128(ln0O, qkv_t, nullptr, nullptr, nullptr, QKV, ROWS, 960, DIM, QK_EXP2_SCALE, 320);
    vtrans_kernel<<<dim3(SPATIAL / 32, 16), 256, 0, stream>>>(QKV, VTs, 960, 640, SPATIAL, SPATIAL);
    flash_kernel<SELF_PARTS, true><<<dim3(SPATIAL / TQ, NHEADS, BATCH * SELF_PARTS), 256, 0, stream>>>(
        QKV, QKV + 320, VTs, nullptr, Opart, Lpart, 960, 960, SPATIAL, SPATIAL);
    attn_merge_kernel<<<ROWS, 320, 0, stream>>>(Opart, Lpart, attnO);
    gemm64(attnO, a1wo_t, a1_bo, B0, B0, nullptr, ROWS, DIM, DIM);

    // ---- cross-attention ----
    ln_kernel<<<ROWS / 4, 256, 0, stream>>>(B0, ln1_s, ln1_b, ln1O);
    gemm64(ln1O, a2wq_t, nullptr, nullptr, nullptr, Q2, ROWS, DIM, DIM, QK_EXP2_SCALE, 320);
    gemm_small_kernel<<<dim3(3, 10), 256, 0, stream>>>(kvbf, kvx_t, KVc, BATCH * KVL, 640, KVD);
    vtrans_kernel<<<dim3(4, 16), 256, 0, stream>>>(KVc, VTc, 640, 320, KVL, 128);
    flash_kernel<1, false><<<dim3(SPATIAL / TQ, NHEADS, BATCH), 256, 0, stream>>>(
        Q2, KVc, VTc, attnO, nullptr, nullptr, 320, 640, 128, KVL);
    gemm64(attnO, a2wo_t, a2_bo, B0, B0, nullptr, ROWS, DIM, DIM);

    // ---- FFN (GEGLU) ----
    ln_kernel<<<ROWS / 4, 256, 0, stream>>>(B0, lnA_s, lnA_b, lnAO);
    geglu128_kernel<<<dim3(ROWS / 128, FF / 64), 256, 0, stream>>>(lnAO, fc0_t, fc0_b, GLU, ROWS);
    gemm64(GLU, fc1_t, fc1_b, B0, nullptr, X2, ROWS, DIM, FF);

    // ---- conv_out fused with NCHW transpose + res1 ----
    gemm_convout_kernel<<<dim3(ROWS / 64, DIM / 64), 256, 0, stream>>>(
        X2, cout_t, cout_b, q, out);
}

// Round 10
// 358.256 us; speedup vs baseline: 1.2204x; 1.0557x over previous
//
#include <hip/hip_runtime.h>
#include <math.h>

typedef short short8 __attribute__((ext_vector_type(8)));
typedef float floatx4 __attribute__((ext_vector_type(4)));
typedef unsigned short ushort_t;
typedef unsigned short ushort4_t __attribute__((ext_vector_type(4)));
typedef unsigned int uint_t;

// ---- problem constants ----
constexpr int BATCH   = 2;
constexpr int DIM     = 320;
constexpr int NHEADS  = 8;
constexpr int DH      = 40;
constexpr int NGROUPS = 32;
constexpr int CPG     = 10;
constexpr int SPATIAL = 4096;
constexpr int ROWS    = BATCH * SPATIAL;   // 8192
constexpr int KVL     = 77;
constexpr int KVD     = 768;
constexpr int FF      = 1280;              // geglu half width
constexpr int TQ      = 128;               // flash q-tile
constexpr int SELF_PARTS = 4;              // split-K parts for self-attn

// scale(1/sqrt(40)) * log2(e): folded into Q so flash uses exp2 directly
#define QK_EXP2_SCALE 0.2281259062f

__device__ __forceinline__ ushort_t f2bf(float f) {
    uint_t u = __float_as_uint(f);
    u += 0x7FFFu + ((u >> 16) & 1u);       // RNE
    return (ushort_t)(u >> 16);
}
__device__ __forceinline__ float bf2f(ushort_t u) {
    return __uint_as_float(((uint_t)u) << 16);
}

// async global->LDS, 16B per lane; LDS dest = wave-uniform base + lane*16
__device__ __forceinline__ void gld16(const ushort_t* g, ushort_t* l) {
    __builtin_amdgcn_global_load_lds(
        (const __attribute__((address_space(1))) void*)g,
        (__attribute__((address_space(3))) void*)l, 16, 0, 0);
}

// ---------------------------------------------------------------------------
// GroupNorm partial sums: grid (16 slices, 64 groups), atomics into stats.
// ---------------------------------------------------------------------------
__global__ __launch_bounds__(256) void gn_partial_kernel(const float* __restrict__ q,
                                                         float* __restrict__ stats) {
    int slice = blockIdx.x, bg = blockIdx.y;
    const float* base = q + (size_t)bg * (CPG * SPATIAL) + slice * 2560;
    float s = 0.f, ss = 0.f;
#pragma unroll
    for (int j = 0; j < 10; j++) {
        float v = base[j * 256 + threadIdx.x];
        s += v; ss += v * v;
    }
    __shared__ float rs[256], rss[256];
    rs[threadIdx.x] = s; rss[threadIdx.x] = ss;
    __syncthreads();
    for (int off = 128; off > 0; off >>= 1) {
        if (threadIdx.x < off) {
            rs[threadIdx.x]  += rs[threadIdx.x + off];
            rss[threadIdx.x] += rss[threadIdx.x + off];
        }
        __syncthreads();
    }
    if (threadIdx.x == 0) {
        atomicAdd(&stats[bg * 2],     rs[0]);
        atomicAdd(&stats[bg * 2 + 1], rss[0]);
    }
}

__global__ void gn_apply_transpose_kernel(const float* __restrict__ q,
                                          const float* __restrict__ stats,
                                          const float* __restrict__ gs,
                                          const float* __restrict__ gb,
                                          ushort_t* __restrict__ out) {
    __shared__ float tile[32][33];
    int l0 = blockIdx.x * 32, c0 = blockIdx.y * 32, b = blockIdx.z;
    int tx = threadIdx.x, ty = threadIdx.y;
    int c = c0 + ty;
    int g = c / CPG;
    float s  = stats[(b * NGROUPS + g) * 2];
    float ss = stats[(b * NGROUPS + g) * 2 + 1];
    const float invn = 1.f / 40960.f;
    float mean = s * invn;
    float rstd = rsqrtf(ss * invn - mean * mean + 1e-6f);
    float v = q[((size_t)(b * DIM + c)) * SPATIAL + l0 + tx];
    tile[ty][tx] = (v - mean) * rstd * gs[c] + gb[c];
    __syncthreads();
    out[((size_t)(b * SPATIAL + l0 + ty)) * DIM + c0 + tx] = f2bf(tile[tx][ty]);
}

// ---------------------------------------------------------------------------
// LayerNorm rows of 320, f32 in, bf16 out. 8 rows per 512-thread block.
// ---------------------------------------------------------------------------
__global__ __launch_bounds__(512) void ln_kernel(const float* __restrict__ x,
                                                 const float* __restrict__ sc,
                                                 const float* __restrict__ bi,
                                                 ushort_t* __restrict__ out) {
    int row = blockIdx.x * 8 + (threadIdx.x >> 6);
    int lane = threadIdx.x & 63;
    const float* xr = x + (size_t)row * DIM;
    float v[5];
    float sum = 0.f, sq = 0.f;
#pragma unroll
    for (int j = 0; j < 5; j++) {
        v[j] = xr[lane + j * 64];
        sum += v[j]; sq += v[j] * v[j];
    }
#pragma unroll
    for (int off = 32; off > 0; off >>= 1) {
        sum += __shfl_down(sum, off);
        sq  += __shfl_down(sq, off);
    }
    sum = __shfl(sum, 0); sq = __shfl(sq, 0);
    float mean = sum / (float)DIM;
    float rstd = rsqrtf(sq / (float)DIM - mean * mean + 1e-5f);
#pragma unroll
    for (int j = 0; j < 5; j++) {
        int i = lane + j * 64;
        out[(size_t)row * DIM + i] = f2bf((v[j] - mean) * rstd * sc[i] + bi[i]);
    }
}

// ---------------------------------------------------------------------------
// Weight prep fused: 12 transpose segments (f32 [K][N] -> bf16 [N][K]) +
// kv cvt + stats zero + VT static init (self pad rows 40..47; cross full).
// ---------------------------------------------------------------------------
struct WSeg { const float* src; ushort_t* dst; int K; int N; int t0; };
struct WTab {
    WSeg s[12];
    const float* cvt_src; ushort_t* cvt_dst; int cvt_n; int cvt_t0;
    float* stats;
    ushort_t* vts; int vts_t0;    // 64 blocks: rows 40..47 of VTs (ones@40)
    ushort_t* vtc; int vtc_t0;    // 12 blocks: full VTc init (ones@row40)
};

__global__ __launch_bounds__(256) void wtrans_all_kernel(WTab tab) {
    int bid = blockIdx.x;
    if (bid >= tab.vtc_t0) {
        int base = (bid - tab.vtc_t0) * 8192;
#pragma unroll
        for (int j = 0; j < 32; j++) {
            int e = base + j * 256 + threadIdx.x;   // e < 16*48*128 = 98304
            int r = (e >> 7) % 48;
            tab.vtc[e] = (r == 40) ? (ushort_t)0x3F80 : (ushort_t)0;
        }
        return;
    }
    if (bid >= tab.vts_t0) {
        int base = (bid - tab.vts_t0) * 8192;
#pragma unroll
        for (int j = 0; j < 32; j++) {
            int e = base + j * 256 + threadIdx.x;   // e < 16*8*4096 = 524288
            int bh = e >> 15, r = (e >> 12) & 7, col = e & 4095;
            tab.vts[((size_t)(bh * 48 + 40 + r) << 12) + col] =
                (r == 0) ? (ushort_t)0x3F80 : (ushort_t)0;
        }
        return;
    }
    if (bid >= tab.cvt_t0) {
        int local = bid - tab.cvt_t0;
        int base = local * 8192;
#pragma unroll
        for (int j = 0; j < 32; j++) {
            int i = base + j * 256 + threadIdx.x;
            if (i < tab.cvt_n) tab.cvt_dst[i] = f2bf(tab.cvt_src[i]);
        }
        if (local == 0 && threadIdx.x < 128) tab.stats[threadIdx.x] = 0.f;
        return;
    }
    __shared__ float tile[32][33];
    int si = 0;
#pragma unroll
    for (int i = 1; i < 12; i++) if (bid >= tab.s[i].t0) si = i;
    WSeg sg = tab.s[si];
    int local = bid - sg.t0;
    int ntn = sg.N >> 5;
    int kt = local / ntn, nt = local - kt * ntn;
    int n0 = nt * 32, k0 = kt * 32;
    int tx = threadIdx.x & 31, ty8 = threadIdx.x >> 5;
    for (int r = ty8; r < 32; r += 8)
        tile[r][tx] = sg.src[(size_t)(k0 + r) * sg.N + n0 + tx];
    __syncthreads();
    for (int r = ty8; r < 32; r += 8)
        sg.dst[(size_t)(n0 + r) * sg.K + k0 + tx] = f2bf(tile[tx][r]);
}

// ---------------------------------------------------------------------------
// bf16 MFMA GEMM, templated M-tile (64 or 128) x 64(N) x 64(K) steps.
// global_load_lds + XOR-swizzled unpadded LDS.
// ---------------------------------------------------------------------------
template <int TM>
__global__ __launch_bounds__(256) void gemm_bf16_kernel(
    const ushort_t* __restrict__ A, const ushort_t* __restrict__ Wt,
    const float* __restrict__ bias, const float* __restrict__ resid,
    float* __restrict__ Cf, ushort_t* __restrict__ Cb,
    int M, int N, int K, float qsc, int ncut)
{
    constexpr int G = TM / 64;          // row-groups per wave
    __shared__ __align__(16) ushort_t As[TM][64];
    __shared__ __align__(16) ushort_t Bs[64][64];
    int tid = threadIdx.x;
    int wave = tid >> 6, lane = tid & 63;
    int l15 = tid & 15, quad = lane >> 4;
    int m0 = blockIdx.x * TM, n0 = blockIdx.y * 64;
    int lrow = lane >> 3, slot = lane & 7;
    floatx4 acc[G][4] = {};

    for (int k0 = 0; k0 < K; k0 += 64) {
#pragma unroll
        for (int t = 0; t < TM / 32; t++) {
            int task = wave * (TM / 32) + t;
            int r = task * 8 + lrow;
            int gc = slot ^ (r & 7);
            gld16(&A[(size_t)(m0 + r) * K + k0 + gc * 8], &As[task * 8][0]);
        }
#pragma unroll
        for (int t = 0; t < 2; t++) {
            int task = wave * 2 + t;
            int r = task * 8 + lrow;
            int gc = slot ^ (r & 7);
            gld16(&Wt[(size_t)(n0 + r) * K + k0 + gc * 8], &Bs[task * 8][0]);
        }
        __syncthreads();
        short8 a[G][2], b[4][2];
#pragma unroll
        for (int g = 0; g < G; g++) {
            int r = (TM / 4) * wave + 16 * g + l15;
            a[g][0] = *(const short8*)&As[r][(quad ^ (r & 7)) * 8];
            a[g][1] = *(const short8*)&As[r][((4 + quad) ^ (r & 7)) * 8];
        }
#pragma unroll
        for (int t = 0; t < 4; t++) {
            int r = 16 * t + l15;
            b[t][0] = *(const short8*)&Bs[r][(quad ^ (r & 7)) * 8];
            b[t][1] = *(const short8*)&Bs[r][((4 + quad) ^ (r & 7)) * 8];
        }
#pragma unroll
        for (int g = 0; g < G; g++)
#pragma unroll
            for (int t = 0; t < 4; t++) {
                acc[g][t] = __builtin_amdgcn_mfma_f32_16x16x32_bf16(a[g][0], b[t][0], acc[g][t], 0, 0, 0);
                acc[g][t] = __builtin_amdgcn_mfma_f32_16x16x32_bf16(a[g][1], b[t][1], acc[g][t], 0, 0, 0);
            }
        __syncthreads();
    }

#pragma unroll
    for (int g = 0; g < G; g++) {
        int mrow = m0 + (TM / 4) * wave + 16 * g + quad * 4;
#pragma unroll
        for (int t = 0; t < 4; t++) {
            int n = n0 + 16 * t + l15;
            float bv = bias ? bias[n] : 0.f;
            float sc = (n < ncut) ? qsc : 1.f;
#pragma unroll
            for (int i = 0; i < 4; i++) {
                int m = mrow + i;
                float v = acc[g][t][i] + bv;
                if (resid) v += resid[(size_t)m * N + n];
                v *= sc;
                if (Cf) Cf[(size_t)m * N + n] = v;
                if (Cb) Cb[(size_t)m * N + n] = f2bf(v);
            }
        }
    }
}

// ---------------------------------------------------------------------------
// QKV projection GEMM (TM=128, N=960, K=320): Q cols (<320) scaled by
// QK_EXP2_SCALE; Q/K cols written to QKV buffer; V cols (>=640) written
// DIRECTLY TRANSPOSED into VTs[bh][48][4096] (pad rows pre-initialized).
// ---------------------------------------------------------------------------
__global__ __launch_bounds__(256) void gemm_qkv_kernel(
    const ushort_t* __restrict__ A, const ushort_t* __restrict__ Wt,
    ushort_t* __restrict__ Cqk, ushort_t* __restrict__ VTdst)
{
    constexpr int K = 320, N = 960;
    __shared__ __align__(16) ushort_t As[128][64];
    __shared__ __align__(16) ushort_t Bs[64][64];
    int tid = threadIdx.x;
    int wave = tid >> 6, lane = tid & 63;
    int l15 = tid & 15, quad = lane >> 4;
    int m0 = blockIdx.x * 128, n0 = blockIdx.y * 64;
    int lrow = lane >> 3, slot = lane & 7;
    floatx4 acc[2][4] = {};

    for (int k0 = 0; k0 < K; k0 += 64) {
#pragma unroll
        for (int t = 0; t < 4; t++) {
            int task = wave * 4 + t;
            int r = task * 8 + lrow;
            int gc = slot ^ (r & 7);
            gld16(&A[(size_t)(m0 + r) * K + k0 + gc * 8], &As[task * 8][0]);
        }
#pragma unroll
        for (int t = 0; t < 2; t++) {
            int task = wave * 2 + t;
            int r = task * 8 + lrow;
            int gc = slot ^ (r & 7);
            gld16(&Wt[(size_t)(n0 + r) * K + k0 + gc * 8], &Bs[task * 8][0]);
        }
        __syncthreads();
        short8 a[2][2], b[4][2];
#pragma unroll
        for (int g = 0; g < 2; g++) {
            int r = 32 * wave + 16 * g + l15;
            a[g][0] = *(const short8*)&As[r][(quad ^ (r & 7)) * 8];
            a[g][1] = *(const short8*)&As[r][((4 + quad) ^ (r & 7)) * 8];
        }
#pragma unroll
        for (int t = 0; t < 4; t++) {
            int r = 16 * t + l15;
            b[t][0] = *(const short8*)&Bs[r][(quad ^ (r & 7)) * 8];
            b[t][1] = *(const short8*)&Bs[r][((4 + quad) ^ (r & 7)) * 8];
        }
#pragma unroll
        for (int g = 0; g < 2; g++)
#pragma unroll
            for (int t = 0; t < 4; t++) {
                acc[g][t] = __builtin_amdgcn_mfma_f32_16x16x32_bf16(a[g][0], b[t][0], acc[g][t], 0, 0, 0);
                acc[g][t] = __builtin_amdgcn_mfma_f32_16x16x32_bf16(a[g][1], b[t][1], acc[g][t], 0, 0, 0);
            }
        __syncthreads();
    }

    int bq = m0 >> 12;                 // batch (128 | 4096)
#pragma unroll
    for (int g = 0; g < 2; g++) {
        int mrow = m0 + 32 * wave + 16 * g + quad * 4;
#pragma unroll
        for (int t = 0; t < 4; t++) {
            int n = n0 + 16 * t + l15;
            if (n < 640) {
                float sc = (n < 320) ? QK_EXP2_SCALE : 1.f;
#pragma unroll
                for (int i = 0; i < 4; i++)
                    Cqk[(size_t)(mrow + i) * N + n] = f2bf(acc[g][t][i] * sc);
            } else {
                int hd = n - 640;
                int h = hd / DH, d = hd - h * DH;
                int l = (mrow & 4095);             // 4 consecutive rows, 8B aligned
                ushort4_t v4;
#pragma unroll
                for (int i = 0; i < 4; i++) v4[i] = f2bf(acc[g][t][i]);
                *(ushort4_t*)&VTdst[((size_t)((bq * NHEADS + h) * 48 + d) << 12) + l] = v4;
            }
        }
    }
}

// ---------------------------------------------------------------------------
// fc0+GEGLU on the 128-tile structure: dual B (value n0.., gate FF+n0..)
// ---------------------------------------------------------------------------
__global__ __launch_bounds__(256) void geglu128_kernel(
    const ushort_t* __restrict__ A, const ushort_t* __restrict__ Wt,
    const float* __restrict__ bias, ushort_t* __restrict__ C, int M)
{
    constexpr int K = 320;
    __shared__ __align__(16) ushort_t As[128][64];
    __shared__ __align__(16) ushort_t Bv[64][64];
    __shared__ __align__(16) ushort_t Bg[64][64];
    int tid = threadIdx.x;
    int wave = tid >> 6, lane = tid & 63;
    int l15 = tid & 15, quad = lane >> 4;
    int m0 = blockIdx.x * 128, n0 = blockIdx.y * 64;
    int lrow = lane >> 3, slot = lane & 7;
    floatx4 av[2][4] = {}, ag[2][4] = {};

    for (int k0 = 0; k0 < K; k0 += 64) {
#pragma unroll
        for (int t = 0; t < 4; t++) {
            int task = wave * 4 + t;
            int r = task * 8 + lrow;
            int gc = slot ^ (r & 7);
            gld16(&A[(size_t)(m0 + r) * K + k0 + gc * 8], &As[task * 8][0]);
        }
#pragma unroll
        for (int t = 0; t < 2; t++) {
            int task = wave * 2 + t;
            int r = task * 8 + lrow;
            int gc = slot ^ (r & 7);
            gld16(&Wt[(size_t)(n0 + r) * K + k0 + gc * 8],      &Bv[task * 8][0]);
            gld16(&Wt[(size_t)(FF + n0 + r) * K + k0 + gc * 8], &Bg[task * 8][0]);
        }
        __syncthreads();
        short8 a[2][2], bv[4][2], bg[4][2];
#pragma unroll
        for (int g = 0; g < 2; g++) {
            int r = 32 * wave + 16 * g + l15;
            a[g][0] = *(const short8*)&As[r][(quad ^ (r & 7)) * 8];
            a[g][1] = *(const short8*)&As[r][((4 + quad) ^ (r & 7)) * 8];
        }
#pragma unroll
        for (int t = 0; t < 4; t++) {
            int r = 16 * t + l15;
            bv[t][0] = *(const short8*)&Bv[r][(quad ^ (r & 7)) * 8];
            bv[t][1] = *(const short8*)&Bv[r][((4 + quad) ^ (r & 7)) * 8];
            bg[t][0] = *(const short8*)&Bg[r][(quad ^ (r & 7)) * 8];
            bg[t][1] = *(const short8*)&Bg[r][((4 + quad) ^ (r & 7)) * 8];
        }
#pragma unroll
        for (int g = 0; g < 2; g++)
#pragma unroll
            for (int t = 0; t < 4; t++) {
                av[g][t] = __builtin_amdgcn_mfma_f32_16x16x32_bf16(a[g][0], bv[t][0], av[g][t], 0, 0, 0);
                av[g][t] = __builtin_amdgcn_mfma_f32_16x16x32_bf16(a[g][1], bv[t][1], av[g][t], 0, 0, 0);
                ag[g][t] = __builtin_amdgcn_mfma_f32_16x16x32_bf16(a[g][0], bg[t][0], ag[g][t], 0, 0, 0);
                ag[g][t] = __builtin_amdgcn_mfma_f32_16x16x32_bf16(a[g][1], bg[t][1], ag[g][t], 0, 0, 0);
            }
        __syncthreads();
    }

#pragma unroll
    for (int g = 0; g < 2; g++) {
        int mrow = m0 + 32 * wave + 16 * g + quad * 4;
#pragma unroll
        for (int t = 0; t < 4; t++) {
            int n = n0 + 16 * t + l15;
            float bb = bias[n], bgte = bias[FF + n];
#pragma unroll
            for (int i = 0; i < 4; i++) {
                float val  = av[g][t][i] + bb;
                float gate = ag[g][t][i] + bgte;
                float gl = 0.5f * gate * (1.f + erff(gate * 0.70710678118654752f));
                C[(size_t)(mrow + i) * FF + n] = f2bf(val * gl);
            }
        }
    }
}

// ---------------------------------------------------------------------------
// conv_out fused with NCHW transpose + res1.
// ---------------------------------------------------------------------------
__global__ __launch_bounds__(256) void gemm_convout_kernel(
    const ushort_t* __restrict__ A, const ushort_t* __restrict__ Wt,
    const float* __restrict__ bias, const float* __restrict__ qres,
    float* __restrict__ out)
{
    constexpr int K = 320;
    __shared__ __align__(16) ushort_t As[64][64];
    __shared__ __align__(16) ushort_t Bs[64][64];
    __shared__ float Cf[64][68];
    int tid = threadIdx.x;
    int wave = tid >> 6, lane = tid & 63;
    int l15 = tid & 15, quad = lane >> 4;
    int m0 = blockIdx.x * 64, n0 = blockIdx.y * 64;
    int lrow = lane >> 3, slot = lane & 7;
    floatx4 acc[4] = {};

    for (int k0 = 0; k0 < K; k0 += 64) {
#pragma unroll
        for (int t = 0; t < 2; t++) {
            int task = wave * 2 + t;
            int r = task * 8 + lrow;
            int gc = slot ^ (r & 7);
            gld16(&A[(size_t)(m0 + r) * K + k0 + gc * 8], &As[task * 8][0]);
            gld16(&Wt[(size_t)(n0 + r) * K + k0 + gc * 8], &Bs[task * 8][0]);
        }
        __syncthreads();
        short8 a0, a1, b[4][2];
        {
            int r = 16 * wave + l15;
            a0 = *(const short8*)&As[r][(quad ^ (r & 7)) * 8];
            a1 = *(const short8*)&As[r][((4 + quad) ^ (r & 7)) * 8];
        }
#pragma unroll
        for (int t = 0; t < 4; t++) {
            int r = 16 * t + l15;
            b[t][0] = *(const short8*)&Bs[r][(quad ^ (r & 7)) * 8];
            b[t][1] = *(const short8*)&Bs[r][((4 + quad) ^ (r & 7)) * 8];
        }
#pragma unroll
        for (int t = 0; t < 4; t++) {
            acc[t] = __builtin_amdgcn_mfma_f32_16x16x32_bf16(a0, b[t][0], acc[t], 0, 0, 0);
            acc[t] = __builtin_amdgcn_mfma_f32_16x16x32_bf16(a1, b[t][1], acc[t], 0, 0, 0);
        }
        __syncthreads();
    }

#pragma unroll
    for (int t = 0; t < 4; t++) {
        int n = 16 * t + l15;
        float bv = bias[n0 + n];
        int mbase = 16 * wave + 4 * quad;
#pragma unroll
        for (int i = 0; i < 4; i++)
            Cf[n][mbase + i] = acc[t][i] + bv;
    }
    __syncthreads();
    {
        int n = tid >> 2, j = tid & 3;
        int bq = m0 >> 12;
        int l0 = m0 & 4095;
        size_t goff = ((size_t)(bq * DIM + n0 + n)) * SPATIAL + l0 + j * 16;
        const float4* qr = (const float4*)(qres + goff);
        float4* op = (float4*)(out + goff);
#pragma unroll
        for (int c = 0; c < 4; c++) {
            float4 v = *(const float4*)&Cf[n][j * 16 + c * 4];
            float4 qv = qr[c];
            v.x += qv.x; v.y += qv.y; v.z += qv.z; v.w += qv.w;
            op[c] = v;
        }
    }
}

// ---------------------------------------------------------------------------
// Cross K/V projection GEMM (M=154, N=640, K=768): K cols (<320) written to
// KVc (stride 640); V cols (>=320) scattered transposed into VTc[bh][48][128]
// (pad content pre-initialized by weight-prep).
// ---------------------------------------------------------------------------
__global__ __launch_bounds__(256) void gemm_kvx_kernel(
    const ushort_t* __restrict__ A, const ushort_t* __restrict__ Wt,
    ushort_t* __restrict__ Cb, ushort_t* __restrict__ VTc, int M, int N, int K)
{
    __shared__ __align__(16) ushort_t As[64][72];
    __shared__ __align__(16) ushort_t Bs[64][72];
    int tid = threadIdx.x;
    int wave = tid >> 6, l15 = tid & 15, quad = (tid & 63) >> 4;
    int m0 = blockIdx.x * 64, n0 = blockIdx.y * 64;
    floatx4 acc[4] = {};

    for (int k0 = 0; k0 < K; k0 += 64) {
#pragma unroll
        for (int p = 0; p < 2; p++) {
            int lin = p * 256 + tid;
            int r = lin >> 3, c8 = (lin & 7) * 8;
            int m = m0 + r;
            short8 avv = {};
            if (m < M) avv = *(const short8*)&A[(size_t)m * K + k0 + c8];
            *(short8*)&As[r][c8] = avv;
            *(short8*)&Bs[r][c8] = *(const short8*)&Wt[(size_t)(n0 + r) * K + k0 + c8];
        }
        __syncthreads();
        short8 a0 = *(const short8*)&As[16 * wave + l15][quad * 8];
        short8 a1 = *(const short8*)&As[16 * wave + l15][32 + quad * 8];
#pragma unroll
        for (int t = 0; t < 4; t++) {
            short8 b0 = *(const short8*)&Bs[16 * t + l15][quad * 8];
            short8 b1 = *(const short8*)&Bs[16 * t + l15][32 + quad * 8];
            acc[t] = __builtin_amdgcn_mfma_f32_16x16x32_bf16(a0, b0, acc[t], 0, 0, 0);
            acc[t] = __builtin_amdgcn_mfma_f32_16x16x32_bf16(a1, b1, acc[t], 0, 0, 0);
        }
        __syncthreads();
    }
    int mrow = m0 + 16 * wave + quad * 4;
#pragma unroll
    for (int t = 0; t < 4; t++) {
        int n = n0 + 16 * t + l15;
        if (n < 320) {
#pragma unroll
            for (int i = 0; i < 4; i++) {
                int m = mrow + i;
                if (m < M) Cb[(size_t)m * N + n] = f2bf(acc[t][i]);
            }
        } else {
            int hd = n - 320;
            int h = hd / DH, d = hd - h * DH;
#pragma unroll
            for (int i = 0; i < 4; i++) {
                int m = mrow + i;
                if (m < M) {
                    int b = (m >= KVL) ? 1 : 0;
                    int l = m - b * KVL;
                    VTc[((size_t)((b * NHEADS + h) * 48 + d) << 7) + l] = f2bf(acc[t][i]);
                }
            }
        }
    }
}

// ---------------------------------------------------------------------------
// Flash attention v5.1 (same as v5; V-fragment reads hoisted above exp2).
// ---------------------------------------------------------------------------
template <int NPARTS, bool FULL>
__global__ __launch_bounds__(256) void flash_kernel(
    const ushort_t* __restrict__ Qg, const ushort_t* __restrict__ Kg,
    const ushort_t* __restrict__ VT, ushort_t* __restrict__ Og,
    ushort_t* __restrict__ Opart, float* __restrict__ Lpart,
    int sQ, int sKV, int Lpad, int nk)
{
    __shared__ __align__(16) ushort_t QPs[8][130][8];   // Q rows 0..127, then P
    __shared__ __align__(16) ushort_t Ks[8][64][8];
    __shared__ __align__(16) ushort_t VsT[48][64];      // [dh][key], key-chunks XOR-swizzled

    int tid = threadIdx.x;
    int wave = tid >> 6, lane = tid & 63;
    int l15 = tid & 15, quad = lane >> 4;
    int qt = blockIdx.x, h = blockIdx.y;
    int b, kp;
    if (NPARTS > 1) { b = blockIdx.z / NPARTS; kp = blockIdx.z % NPARTS; }
    else            { b = blockIdx.z;          kp = 0; }
    int q0 = qt * TQ;

    const ushort_t* Qb  = Qg + (size_t)(b * SPATIAL + q0) * sQ + h * DH;
    const ushort_t* Kb  = Kg + (size_t)b * nk * sKV + h * DH;
    const ushort_t* VTb = VT + (size_t)(b * NHEADS + h) * 48 * Lpad;

    // zero pad chunks ONCE: Ks 5..7 AND QPs 5..7 (NaN fix: aq[g][1] reads
    // QPs planes 4..7; stale LDS f32 data can alias bf16 NaN -> 0*NaN=NaN)
    const short8 z8 = {};
    for (int i = tid; i < 3 * 64; i += 256)
        *(short8*)&Ks[5 + (i >> 6)][i & 63][0] = z8;
    for (int i = tid; i < 3 * 130; i += 256)
        *(short8*)&QPs[5 + i / 130][i % 130][0] = z8;

    // stage Q: 10 wave-tasks of 64 rows x 16B
    for (int t5 = wave; t5 < 10; t5 += 4) {
        int cid = t5 >> 1, half = t5 & 1;
        gld16(&Qb[(size_t)(half * 64 + lane) * sQ + cid * 8], &QPs[cid][half * 64][0]);
    }
    __syncthreads();

    short8 aq[2][2];
#pragma unroll
    for (int g = 0; g < 2; g++) {
        int r = 32 * wave + 16 * g + l15;
        aq[g][0] = *(const short8*)&QPs[quad][r][0];
        aq[g][1] = *(const short8*)&QPs[4 + quad][r][0];
    }

    // tile-invariant P pointers (element strides: plane=1040, row=8)
    ushort_t* pw = &QPs[l15 >> 3][32 * wave + 4 * quad][l15 & 7];
    const ushort_t* pr = &QPs[quad][32 * wave + l15][0];

    floatx4 o[2][3] = {};

    int ntiles_all = (nk + 63) >> 6;
    int per = ntiles_all / NPARTS;
    int t_lo = kp * per;
    int t_hi = (NPARTS > 1) ? t_lo + per : ntiles_all;

    for (int t = t_lo; t < t_hi; t++) {
        int k0 = t * 64;
        __syncthreads();
        for (int c = wave; c < 5; c += 4)
            gld16(&Kb[(size_t)(k0 + lane) * sKV + c * 8], &Ks[c][0][0]);
        for (int c = wave; c < 6; c += 4) {
            int r8 = lane >> 3;
            int gc = (lane & 7) ^ r8;
            gld16(&VTb[(size_t)(c * 8 + r8) * Lpad + k0 + gc * 8], &VsT[c * 8][0]);
        }
        __syncthreads();

        // S' = (Q*scale*log2e) K^T
        floatx4 s[2][4] = {};
#pragma unroll
        for (int tt = 0; tt < 4; tt++) {
            short8 b0 = *(const short8*)&Ks[quad][16 * tt + l15][0];
            short8 b1 = *(const short8*)&Ks[4 + quad][16 * tt + l15][0];
#pragma unroll
            for (int g = 0; g < 2; g++) {
                s[g][tt] = __builtin_amdgcn_mfma_f32_16x16x32_bf16(aq[g][0], b0, s[g][tt], 0, 0, 0);
                s[g][tt] = __builtin_amdgcn_mfma_f32_16x16x32_bf16(aq[g][1], b1, s[g][tt], 0, 0, 0);
            }
        }

        // hoist V-fragment reads (independent of P) to overlap exp2 latency
        short8 vb[3][2];
#pragma unroll
        for (int t2 = 0; t2 < 3; t2++) {
            int R = 16 * t2 + l15;
            vb[t2][0] = *(const short8*)&VsT[R][(quad ^ (l15 & 7)) * 8];
            vb[t2][1] = *(const short8*)&VsT[R][((4 + quad) ^ (l15 & 7)) * 8];
        }

        // p = exp2(s'), trunc-bf16, compile-time-offset scatter
#pragma unroll
        for (int g = 0; g < 2; g++) {
#pragma unroll
            for (int i = 0; i < 4; i++) {
#pragma unroll
                for (int tt = 0; tt < 4; tt++) {
                    float x = s[g][tt][i];
                    if (!FULL && (k0 + 16 * tt + l15 >= nk)) x = -1e30f;
                    float pf = __builtin_amdgcn_exp2f(x);
                    pw[tt * 2080 + g * 128 + i * 8] =
                        (ushort_t)(__float_as_uint(pf) >> 16);
                }
            }
        }

        // O += P @ [V | 1]; col 40 accumulates l. P rows wave-private.
#pragma unroll
        for (int g = 0; g < 2; g++) {
            short8 p0 = *(const short8*)(pr + g * 128);
            short8 p1 = *(const short8*)(pr + 4 * 1040 + g * 128);
#pragma unroll
            for (int t2 = 0; t2 < 3; t2++) {
                o[g][t2] = __builtin_amdgcn_mfma_f32_16x16x32_bf16(p0, vb[t2][0], o[g][t2], 0, 0, 0);
                o[g][t2] = __builtin_amdgcn_mfma_f32_16x16x32_bf16(p1, vb[t2][1], o[g][t2], 0, 0, 0);
            }
        }
    }

    if (NPARTS == 1) {
        float inv[2][4];
#pragma unroll
        for (int g = 0; g < 2; g++)
#pragma unroll
            for (int i = 0; i < 4; i++)
                inv[g][i] = 1.f / __shfl(o[g][2][i], (lane & 48) | 8, 64);
#pragma unroll
        for (int g = 0; g < 2; g++)
#pragma unroll
            for (int t2 = 0; t2 < 3; t2++) {
                int c = 16 * t2 + l15;
                if (c < DH) {
#pragma unroll
                    for (int i = 0; i < 4; i++) {
                        size_t row = (size_t)(b * SPATIAL + q0 + 32 * wave + 16 * g + 4 * quad + i);
                        Og[row * DIM + h * DH + c] = f2bf(o[g][t2][i] * inv[g][i]);
                    }
                }
            }
    } else {
#pragma unroll
        for (int g = 0; g < 2; g++) {
#pragma unroll
            for (int t2 = 0; t2 < 3; t2++) {
                int c = 16 * t2 + l15;
                if (c < DH) {
#pragma unroll
                    for (int i = 0; i < 4; i++) {
                        size_t row = (size_t)(b * SPATIAL + q0 + 32 * wave + 16 * g + 4 * quad + i);
                        Opart[((size_t)kp * ROWS + row) * DIM + h * DH + c] = f2bf(o[g][t2][i]);
                    }
                }
            }
            if (l15 == 8) {
#pragma unroll
                for (int i = 0; i < 4; i++) {
                    size_t row = (size_t)(b * SPATIAL + q0 + 32 * wave + 16 * g + 4 * quad + i);
                    Lpart[((size_t)kp * ROWS + row) * NHEADS + h] = o[g][2][i];
                }
            }
        }
    }
}

// merge split-K partials: out = (Σ o_kp) / (Σ l_kp); 4 rows per 320-thread
// block, ushort4 vectorized (DH=40 is 4-aligned so a 4-col group shares h).
__global__ __launch_bounds__(320) void attn_merge_kernel(
    const ushort_t* __restrict__ Op, const float* __restrict__ Lp,
    ushort_t* __restrict__ Og)
{
    int t = threadIdx.x;
    int row = blockIdx.x * 4 + t / 80;
    int c = (t % 80) * 4;
    int h = c / DH;
    float l = 0.f;
    float o[4] = {};
#pragma unroll
    for (int kp = 0; kp < SELF_PARTS; kp++) {
        l += Lp[((size_t)kp * ROWS + row) * NHEADS + h];
        ushort4_t v = *(const ushort4_t*)&Op[((size_t)kp * ROWS + row) * DIM + c];
#pragma unroll
        for (int j = 0; j < 4; j++) o[j] += bf2f(v[j]);
    }
    float inv = 1.f / l;
    ushort4_t r;
#pragma unroll
    for (int j = 0; j < 4; j++) r[j] = f2bf(o[j] * inv);
    *(ushort4_t*)&Og[(size_t)row * DIM + c] = r;
}

// ---------------------------------------------------------------------------
extern "C" void kernel_launch(void* const* d_in, const int* in_sizes, int n_in,
                              void* d_out, int out_size, void* d_ws, size_t ws_size,
                              hipStream_t stream) {
    (void)in_sizes; (void)n_in; (void)out_size; (void)ws_size;
    const float* q      = (const float*)d_in[0];
    const float* kv     = (const float*)d_in[1];
    const float* gn_s   = (const float*)d_in[2];
    const float* gn_b   = (const float*)d_in[3];
    const float* cin_w  = (const float*)d_in[4];
    const float* cin_b  = (const float*)d_in[5];
    const float* ln0_s  = (const float*)d_in[6];
    const float* ln0_b  = (const float*)d_in[7];
    const float* a1_wq  = (const float*)d_in[8];
    const float* a1_wk  = (const float*)d_in[9];
    const float* a1_wv  = (const float*)d_in[10];
    const float* a1_wo  = (const float*)d_in[11];
    const float* a1_bo  = (const float*)d_in[12];
    const float* ln1_s  = (const float*)d_in[13];
    const float* ln1_b  = (const float*)d_in[14];
    const float* a2_wq  = (const float*)d_in[15];
    const float* a2_wk  = (const float*)d_in[16];
    const float* a2_wv  = (const float*)d_in[17];
    const float* a2_wo  = (const float*)d_in[18];
    const float* a2_bo  = (const float*)d_in[19];
    const float* lnA_s  = (const float*)d_in[20];
    const float* lnA_b  = (const float*)d_in[21];
    const float* fc0_w  = (const float*)d_in[22];
    const float* fc0_b  = (const float*)d_in[23];
    const float* fc1_w  = (const float*)d_in[24];
    const float* fc1_b  = (const float*)d_in[25];
    const float* cout_w = (const float*)d_in[26];
    const float* cout_b = (const float*)d_in[27];
    float* out = (float*)d_out;

    // ---- workspace carve ----
    char* p = (char*)d_ws;
    auto carve = [&](size_t bytes) -> char* {
        char* r = p;
        p += (bytes + 255) & ~(size_t)255;
        return r;
    };
    float*    stats  = (float*)carve(512);
    float*    B0     = (float*)carve((size_t)ROWS * DIM * 4);
    ushort_t* gnO    = (ushort_t*)carve((size_t)ROWS * DIM * 2);
    ushort_t* ln0O   = (ushort_t*)carve((size_t)ROWS * DIM * 2);
    ushort_t* QKV    = (ushort_t*)carve((size_t)ROWS * 960 * 2);
    ushort_t* attnO  = (ushort_t*)carve((size_t)ROWS * DIM * 2);
    ushort_t* ln1O   = (ushort_t*)carve((size_t)ROWS * DIM * 2);
    ushort_t* Q2     = (ushort_t*)carve((size_t)ROWS * DIM * 2);
    ushort_t* KVc    = (ushort_t*)carve((size_t)BATCH * KVL * 640 * 2);
    ushort_t* lnAO   = (ushort_t*)carve((size_t)ROWS * DIM * 2);
    ushort_t* GLU    = (ushort_t*)carve((size_t)ROWS * FF * 2);
    ushort_t* X2     = (ushort_t*)carve((size_t)ROWS * DIM * 2);
    ushort_t* kvbf   = (ushort_t*)carve((size_t)BATCH * KVL * KVD * 2);
    ushort_t* VTs    = (ushort_t*)carve((size_t)16 * 48 * SPATIAL * 2);  // self V^T
    ushort_t* VTc    = (ushort_t*)carve((size_t)16 * 48 * 128 * 2);      // cross V^T
    ushort_t* qkv_t  = (ushort_t*)carve((size_t)960 * 320 * 2);
    ushort_t* cin_t  = (ushort_t*)carve((size_t)320 * 320 * 2);
    ushort_t* a1wo_t = (ushort_t*)carve((size_t)320 * 320 * 2);
    ushort_t* a2wq_t = (ushort_t*)carve((size_t)320 * 320 * 2);
    ushort_t* kvx_t  = (ushort_t*)carve((size_t)640 * 768 * 2);
    ushort_t* a2wo_t = (ushort_t*)carve((size_t)320 * 320 * 2);
    ushort_t* fc0_t  = (ushort_t*)carve((size_t)2560 * 320 * 2);
    ushort_t* fc1_t  = (ushort_t*)carve((size_t)320 * 1280 * 2);
    ushort_t* cout_t = (ushort_t*)carve((size_t)320 * 320 * 2);
    // split-K partials alias phase-disjoint buffers:
    ushort_t* Opart = GLU;           // 4 * ROWS * DIM * 2 B = 21.0 MB == GLU
    float*    Lpart = (float*)gnO;   // 4 * ROWS * 8 f32 = 1.05 MB <= gnO 5.2 MB

    auto gemm64 = [&](const ushort_t* A, const ushort_t* Wt, const float* bias,
                      const float* resid, float* Cf, ushort_t* Cb,
                      int M, int N, int K, float qsc = 1.f, int ncut = 0) {
        gemm_bf16_kernel<64><<<dim3(M / 64, N / 64), 256, 0, stream>>>(
            A, Wt, bias, resid, Cf, Cb, M, N, K, qsc, ncut);
    };

    // ---- fused weight prep (+ kv cvt + stats zero + VT static init) ----
    {
        WTab tab;
        int t0 = 0;
        auto seg = [&](int i, const float* s, ushort_t* d, int K, int N) {
            tab.s[i] = {s, d, K, N, t0};
            t0 += (K / 32) * (N / 32);
        };
        seg(0,  cin_w,  cin_t,             320, 320);
        seg(1,  a1_wq,  qkv_t,             320, 320);
        seg(2,  a1_wk,  qkv_t + 320 * 320, 320, 320);
        seg(3,  a1_wv,  qkv_t + 640 * 320, 320, 320);
        seg(4,  a1_wo,  a1wo_t,            320, 320);
        seg(5,  a2_wq,  a2wq_t,            320, 320);
        seg(6,  a2_wk,  kvx_t,             768, 320);
        seg(7,  a2_wv,  kvx_t + 320 * 768, 768, 320);
        seg(8,  a2_wo,  a2wo_t,            320, 320);
        seg(9,  fc0_w,  fc0_t,             320, 2560);
        seg(10, fc1_w,  fc1_t,             1280, 320);
        seg(11, cout_w, cout_t,            320, 320);
        tab.cvt_src = kv; tab.cvt_dst = kvbf;
        tab.cvt_n = BATCH * KVL * KVD; tab.cvt_t0 = t0;
        tab.stats = stats;
        int ncvt = (tab.cvt_n + 8191) / 8192;
        tab.vts = VTs; tab.vts_t0 = t0 + ncvt;
        tab.vtc = VTc; tab.vtc_t0 = tab.vts_t0 + 64;   // 16*8*4096/8192 = 64
        int nblk = tab.vtc_t0 + 12;                    // 16*48*128/8192 = 12
        wtrans_all_kernel<<<nblk, 256, 0, stream>>>(tab);
    }

    // ---- GroupNorm + conv_in ----
    gn_partial_kernel<<<dim3(16, 64), 256, 0, stream>>>(q, stats);
    gn_apply_transpose_kernel<<<dim3(SPATIAL / 32, DIM / 32, BATCH), dim3(32, 32), 0, stream>>>(
        q, stats, gn_s, gn_b, gnO);
    gemm64(gnO, cin_t, cin_b, nullptr, B0, nullptr, ROWS, DIM, DIM);

    // ---- self-attention (split-K x4 flash; V transposed in QKV epilogue) ----
    ln_kernel<<<ROWS / 8, 512, 0, stream>>>(B0, ln0_s, ln0_b, ln0O);
    gemm_qkv_kernel<<<dim3(ROWS / 128, 960 / 64), 256, 0, stream>>>(ln0O, qkv_t, QKV, VTs);
    flash_kernel<SELF_PARTS, true><<<dim3(SPATIAL / TQ, NHEADS, BATCH * SELF_PARTS), 256, 0, stream>>>(
        QKV, QKV + 320, VTs, nullptr, Opart, Lpart, 960, 960, SPATIAL, SPATIAL);
    attn_merge_kernel<<<ROWS / 4, 320, 0, stream>>>(Opart, Lpart, attnO);
    gemm64(attnO, a1wo_t, a1_bo, B0, B0, nullptr, ROWS, DIM, DIM);

    // ---- cross-attention (V transposed in KV-projection epilogue) ----
    ln_kernel<<<ROWS / 8, 512, 0, stream>>>(B0, ln1_s, ln1_b, ln1O);
    gemm64(ln1O, a2wq_t, nullptr, nullptr, nullptr, Q2, ROWS, DIM, DIM, QK_EXP2_SCALE, 320);
    gemm_kvx_kernel<<<dim3(3, 10), 256, 0, stream>>>(kvbf, kvx_t, KVc, VTc, BATCH * KVL, 640, KVD);
    flash_kernel<1, false><<<dim3(SPATIAL / TQ, NHEADS, BATCH), 256, 0, stream>>>(
        Q2, KVc, VTc, attnO, nullptr, nullptr, 320, 640, 128, KVL);
    gemm64(attnO, a2wo_t, a2_bo, B0, B0, nullptr, ROWS, DIM, DIM);

    // ---- FFN (GEGLU) ----
    ln_kernel<<<ROWS / 8, 512, 0, stream>>>(B0, lnA_s, lnA_b, lnAO);
    geglu128_kernel<<<dim3(ROWS / 128, FF / 64), 256, 0, stream>>>(lnAO, fc0_t, fc0_b, GLU, ROWS);
    gemm64(GLU, fc1_t, fc1_b, B0, nullptr, X2, ROWS, DIM, FF);

    // ---- conv_out fused with NCHW transpose + res1 ----
    gemm_convout_kernel<<<dim3(ROWS / 64, DIM / 64), 256, 0, stream>>>(
        X2, cout_t, cout_b, q, out);
}